// Round 17
// baseline (236.525 us; speedup 1.0000x reference)
//
#include <hip/hip_runtime.h>

// SNN: v_dec = v + 0.1*(i - v); i_dec = 0.8*i; spike if v_dec > 1.0
// v' = spike ? 0 : v_dec; i' = i_dec + input.

#define T_STEPS 32

typedef __bf16 bf16x8 __attribute__((ext_vector_type(8)));
typedef float f32x16 __attribute__((ext_vector_type(16)));
typedef int i32x4 __attribute__((ext_vector_type(4)));

// Bijective XCD-chunked block swizzle (m204).
__device__ __forceinline__ int xcd_swz(int orig, int nwg) {
    const int q = nwg >> 3, r = nwg & 7;
    const int xcd = orig & 7, idx = orig >> 3;
    return (xcd < r ? xcd * (q + 1) : r * (q + 1) + (xcd - r) * q) + idx;
}

// ---------------- K_prep: fused {x-transpose, conv2-wsplit, fc-wsplit} ----------------
// bid <2048: transpose; <2098: k2w; else k3w. All independent -> overlap in one dispatch.
__global__ __launch_bounds__(256) void k_prep(
    const float* __restrict__ x,  float* __restrict__ xT,
    const float* __restrict__ w2, unsigned short* __restrict__ wsplit,
    const float* __restrict__ fw, unsigned short* __restrict__ wf)
{
    __shared__ float tile[32][65];
    const int bid = blockIdx.x;
    const int tid = threadIdx.x;

    if (bid < 2048) {
        // ---- transpose x [t][b][64][64] -> xT [t][y][x][b] ----
        const int y = bid & 63, t = bid >> 6;
        const int lx = tid & 63, bg = tid >> 6;
        #pragma unroll
        for (int p = 0; p < 8; ++p) {
            const int b = bg + p * 4;
            tile[b][lx] = x[((size_t)(t * 32 + b) * 64 + y) * 64 + lx];
        }
        __syncthreads();
        const int wb = tid & 31, xg = tid >> 5;
        #pragma unroll
        for (int p = 0; p < 8; ++p) {
            const int xx = xg + p * 8;
            xT[((size_t)(t * 64 + y) * 64 + xx) * 32 + wb] = tile[wb][xx];
        }
    } else if (bid < 2098) {
        // ---- 3-way bf16 split of conv2 weights ----
        const int i = (bid - 2048) * 256 + tid;
        if (i < 12800) {
            const int co = i / 400, rest = i % 400;
            const int ci = rest / 25, tap = rest % 25;
            const float w = w2[i];
            const unsigned wb = __float_as_uint(w);
            const unsigned hi = wb & 0xFFFF0000u;
            const float r1 = w - __uint_as_float(hi);
            const unsigned mid = __float_as_uint(r1) & 0xFFFF0000u;
            const float r2 = r1 - __uint_as_float(mid);
            const unsigned lo = __float_as_uint(r2) & 0xFFFF0000u;
            const int base = (tap * 32 + co) * 16 + ci;
            wsplit[base]         = (unsigned short)(hi >> 16);
            wsplit[12800 + base] = (unsigned short)(mid >> 16);
            wsplit[25600 + base] = (unsigned short)(lo >> 16);
        }
    } else {
        // ---- 3-way bf16 split of FC weights: wf[3sp][16nt][338ks][32n][16k] ----
        const int gid = (bid - 2098) * 256 + tid;   // 173056 total
        const int l = gid & 31;
        const int ks = (gid >> 5) % 338;
        const int nt = gid / 10816;
        const int n = nt * 32 + l;

        unsigned hipk[8], midpk[8], lopk[8];
        #pragma unroll
        for (int p = 0; p < 8; ++p) {
            unsigned h[2], m[2], o[2];
            #pragma unroll
            for (int e = 0; e < 2; ++e) {
                const float w = (n < 500) ? fw[(size_t)n * 5408 + ks * 16 + 2 * p + e] : 0.f;
                const unsigned wb = __float_as_uint(w);
                const unsigned hi = wb & 0xFFFF0000u;
                const float r1 = w - __uint_as_float(hi);
                const unsigned mid = __float_as_uint(r1) & 0xFFFF0000u;
                const float r2 = r1 - __uint_as_float(mid);
                h[e] = hi >> 16; m[e] = mid >> 16; o[e] = __float_as_uint(r2) >> 16;
            }
            hipk[p]  = h[0] | (h[1] << 16);
            midpk[p] = m[0] | (m[1] << 16);
            lopk[p]  = o[0] | (o[1] << 16);
        }

        i32x4* __restrict__ wv = (i32x4*)wf;
        const int base = (nt * 338 + ks) * 64 + l * 2;  // i32x4 units; sp stride 346112
        i32x4 a, bq;
        a[0]=(int)hipk[0];a[1]=(int)hipk[1];a[2]=(int)hipk[2];a[3]=(int)hipk[3];
        bq[0]=(int)hipk[4];bq[1]=(int)hipk[5];bq[2]=(int)hipk[6];bq[3]=(int)hipk[7];
        wv[base] = a; wv[base + 1] = bq;
        a[0]=(int)midpk[0];a[1]=(int)midpk[1];a[2]=(int)midpk[2];a[3]=(int)midpk[3];
        bq[0]=(int)midpk[4];bq[1]=(int)midpk[5];bq[2]=(int)midpk[6];bq[3]=(int)midpk[7];
        wv[base + 346112] = a; wv[base + 346113] = bq;
        a[0]=(int)lopk[0];a[1]=(int)lopk[1];a[2]=(int)lopk[2];a[3]=(int)lopk[3];
        bq[0]=(int)lopk[4];bq[1]=(int)lopk[5];bq[2]=(int)lopk[6];bq[3]=(int)lopk[7];
        wv[base + 692224] = a; wv[base + 692225] = bq;
    }
}

// ---------------- K1: conv1 (1->16) + LIF + pool, ALL timesteps ----------------
// grid 900 (pos XCD-swizzled), block 256 = 32 b x 8 slots (2 co per slot).
// Pair layout [8tt][18p][32b][2] (2-way bank aliasing = free), 18 ds_read_b64/t.
// T14 async-stage: next chunk's global loads issued into regs BEFORE computing
// current chunk; vmcnt-wait lands after ~2200 VALU ops. 8 barriers total.
__global__ __launch_bounds__(256) void k1_conv1(
    const float* __restrict__ xT,    // [32t,64,64,32b]
    const float* __restrict__ w1,    // [16,1,5,5]
    const float* __restrict__ b1,    // [16]
    unsigned short* __restrict__ zp1c)
{
    const int pos = xcd_swz(blockIdx.x, 900);
    const int py = pos / 30, px = pos % 30;
    const int y0 = 2 * py, x0 = 2 * px;
    const int tid = threadIdx.x;
    const int b = tid & 31, slot = tid >> 5;

    __shared__ float win2[8 * 18 * 64];   // [8tt][18p][32b][2] = 36 KB

    float wreg[2][25];
    #pragma unroll
    for (int k = 0; k < 25; ++k) {
        wreg[0][k] = w1[slot * 25 + k];
        wreg[1][k] = w1[(slot + 8) * 25 + k];
    }
    const float bias0 = b1[slot], bias1 = b1[slot + 8];

    float v[2][4] = {{0.f,0.f,0.f,0.f},{0.f,0.f,0.f,0.f}};
    float cu[2][4] = {{0.f,0.f,0.f,0.f},{0.f,0.f,0.f,0.f}};

    // u16 idx = t*460800 + half*230400 + pos*256 + (slot>>1)*64 + b*2 + (slot&1)
    const size_t obase = (size_t)pos * 256 + (slot >> 1) * 64 + b * 2 + (slot & 1);

    float4 pfA[5], pfB[5];   // prefetch regs: 1152 tasks = 4 full rounds + half round

#define K1_LOAD(cc)                                                          \
    _Pragma("unroll")                                                        \
    for (int ro = 0; ro < 5; ++ro) {                                         \
        if (ro < 4 || tid < 128) {                                           \
            const int i = ro * 256 + tid;                                    \
            const int tt2 = i / 144;                                         \
            const int rem = i - tt2 * 144;                                   \
            const int p = rem >> 3, bq = rem & 7;                            \
            const int r = p / 3, cpair = p - r * 3;                          \
            const float* __restrict__ s0 = xT +                              \
                ((size_t)(((cc) * 8 + tt2) * 64 + y0 + r) * 64 +             \
                 (x0 + 2 * cpair)) * 32 + bq * 4;                            \
            pfA[ro] = *(const float4*)s0;                                    \
            pfB[ro] = *(const float4*)(s0 + 32);                             \
        }                                                                    \
    }

#define K1_WRITE()                                                           \
    _Pragma("unroll")                                                        \
    for (int ro = 0; ro < 5; ++ro) {                                         \
        if (ro < 4 || tid < 128) {                                           \
            const int i = ro * 256 + tid;                                    \
            const int tt2 = i / 144;                                         \
            const int rem = i - tt2 * 144;                                   \
            const int p = rem >> 3, bq = rem & 7;                            \
            float2* __restrict__ d =                                         \
                (float2*)win2 + ((tt2 * 18 + p) * 32 + bq * 4);              \
            d[0] = make_float2(pfA[ro].x, pfB[ro].x);                        \
            d[1] = make_float2(pfA[ro].y, pfB[ro].y);                        \
            d[2] = make_float2(pfA[ro].z, pfB[ro].z);                        \
            d[3] = make_float2(pfA[ro].w, pfB[ro].w);                        \
        }                                                                    \
    }

    K1_LOAD(0);
    K1_WRITE();
    __syncthreads();

    for (int tp = 0; tp < 4; ++tp) {
        if (tp < 3) K1_LOAD(tp + 1);   // in flight during this chunk's compute

        for (int tt = 0; tt < 8; ++tt) {
            const int t = tp * 8 + tt;
            float xr[36];
            #pragma unroll
            for (int p = 0; p < 18; ++p) {
                const float2 u = ((const float2*)win2)[(tt * 18 + p) * 32 + b];
                const int r = p / 3, cpair = p - r * 3;
                xr[r * 6 + 2 * cpair]     = u.x;
                xr[r * 6 + 2 * cpair + 1] = u.y;
            }

            float acc0[4] = {0.f, 0.f, 0.f, 0.f};
            float acc1[4] = {0.f, 0.f, 0.f, 0.f};
            #pragma unroll
            for (int ky = 0; ky < 5; ++ky) {
                #pragma unroll
                for (int kx = 0; kx < 5; ++kx) {
                    const int tap = ky * 5 + kx;
                    const float e00 = xr[ky * 6 + kx];
                    const float e01 = xr[ky * 6 + kx + 1];
                    const float e10 = xr[(ky + 1) * 6 + kx];
                    const float e11 = xr[(ky + 1) * 6 + kx + 1];
                    const float w0 = wreg[0][tap];
                    acc0[0] = fmaf(w0, e00, acc0[0]);
                    acc0[1] = fmaf(w0, e01, acc0[1]);
                    acc0[2] = fmaf(w0, e10, acc0[2]);
                    acc0[3] = fmaf(w0, e11, acc0[3]);
                    const float w1v = wreg[1][tap];
                    acc1[0] = fmaf(w1v, e00, acc1[0]);
                    acc1[1] = fmaf(w1v, e01, acc1[1]);
                    acc1[2] = fmaf(w1v, e10, acc1[2]);
                    acc1[3] = fmaf(w1v, e11, acc1[3]);
                }
            }

            #pragma unroll
            for (int half = 0; half < 2; ++half) {
                const float* acc = half ? acc1 : acc0;
                const float bias = half ? bias1 : bias0;
                float zmax = 0.f;
                #pragma unroll
                for (int q = 0; q < 4; ++q) {
                    const float inp = acc[q] + bias;
                    const float vv = v[half][q], curr = cu[half][q];
                    const float vd = vv + 0.1f * (curr - vv);
                    const float id = 0.8f * curr;
                    const float z = (vd - 1.0f > 0.0f) ? 1.0f : 0.0f;
                    v[half][q] = (z > 0.f) ? 0.f : vd;
                    cu[half][q] = id + inp;
                    zmax = fmaxf(zmax, z);
                }
                zp1c[(size_t)t * 460800 + (size_t)half * 230400 + obase] =
                    (unsigned short)(__float_as_uint(zmax) >> 16);  // bf16 of 0/1 exact
            }
        }

        if (tp < 3) {
            __syncthreads();   // all readers done with win2
            K1_WRITE();        // vmcnt wait happens here, after the compute phase
            __syncthreads();   // next chunk staged
        }
    }
#undef K1_LOAD
#undef K1_WRITE
}

// ---------------- K2a: conv2 as MFMA GEMM (unfused) ----------------
__global__ __launch_bounds__(256, 2) void k2a_mfma(
    const unsigned* __restrict__ zp1c,       // [32t][2cig][30][30][4p][32b] u32
    const unsigned short* __restrict__ wsplit,
    float* __restrict__ raw)                 // [32t][169pg][4q][32co][32b]
{
    __shared__ i32x4 wlds[4800];  // [3sp][25tap][32co][2cig]
    const int tid = threadIdx.x;
    for (int i = tid; i < 4800; i += 256)
        wlds[i] = ((const i32x4*)wsplit)[i];
    __syncthreads();

    const int w = tid >> 6, l = tid & 63;
    const int task = xcd_swz(blockIdx.x, 1352) * 4 + w;
    const int t = task / 169, pg = task % 169;
    const int py = pg / 13, px = pg % 13;
    const int b = l & 31, cig = l >> 5;
    const int abase = (l & 31) * 2 + cig;

    const unsigned* __restrict__ zt =
        zp1c + (size_t)(t * 2 + cig) * 115200 + ((2 * py) * 30 + 2 * px) * 128 + b;

    f32x16 accA, accB, accC, accD;
    #pragma unroll
    for (int r = 0; r < 16; ++r) { accA[r] = 0.f; accB[r] = 0.f; accC[r] = 0.f; accD[r] = 0.f; }

    #pragma unroll
    for (int wy = 0; wy < 6; ++wy) {
        i32x4 bw[6];
        #pragma unroll
        for (int wx = 0; wx < 6; ++wx) {
            const unsigned* __restrict__ c = zt + (wy * 30 + wx) * 128;
            bw[wx][0] = (int)c[0];
            bw[wx][1] = (int)c[32];
            bw[wx][2] = (int)c[64];
            bw[wx][3] = (int)c[96];
        }
        if (wy <= 4) {
            #pragma unroll
            for (int sp = 0; sp < 3; ++sp) {
                #pragma unroll
                for (int kx = 0; kx < 5; ++kx) {
                    const int tap = wy * 5 + kx;
                    const bf16x8 A = __builtin_bit_cast(bf16x8, wlds[(sp * 25 + tap) * 64 + abase]);
                    accA = __builtin_amdgcn_mfma_f32_32x32x16_bf16(
                        A, __builtin_bit_cast(bf16x8, bw[kx]),     accA, 0, 0, 0);
                    accB = __builtin_amdgcn_mfma_f32_32x32x16_bf16(
                        A, __builtin_bit_cast(bf16x8, bw[kx + 1]), accB, 0, 0, 0);
                }
            }
        }
        if (wy >= 1) {
            #pragma unroll
            for (int sp = 0; sp < 3; ++sp) {
                #pragma unroll
                for (int kx = 0; kx < 5; ++kx) {
                    const int tap = (wy - 1) * 5 + kx;
                    const bf16x8 A = __builtin_bit_cast(bf16x8, wlds[(sp * 25 + tap) * 64 + abase]);
                    accC = __builtin_amdgcn_mfma_f32_32x32x16_bf16(
                        A, __builtin_bit_cast(bf16x8, bw[kx]),     accC, 0, 0, 0);
                    accD = __builtin_amdgcn_mfma_f32_32x32x16_bf16(
                        A, __builtin_bit_cast(bf16x8, bw[kx + 1]), accD, 0, 0, 0);
                }
            }
        }
    }

    float* __restrict__ rp = raw + (size_t)(t * 169 + pg) * 4096 + b;
    const int hi = l >> 5;
    #pragma unroll
    for (int r = 0; r < 16; ++r) {
        const int row = (r & 3) + 8 * (r >> 2) + 4 * hi;
        rp[row * 32]        = accA[r];
        rp[1024 + row * 32] = accB[r];
        rp[2048 + row * 32] = accC[r];
        rp[3072 + row * 32] = accD[r];
    }
}

// ---------------- K2b: LIF + pool scan over t; writes packed bf16 zb directly ----------
__global__ __launch_bounds__(256) void k2b_lifpool(
    const float* __restrict__ raw,   // [32t][169pg][4q][32co][32b]
    const float* __restrict__ b2,
    unsigned short* __restrict__ zb) // [32t][338ks][2kh][32b][8k8]
{
    const int bid = blockIdx.x;
    const int pg = bid >> 2, cog = bid & 3;
    const int tid = threadIdx.x;
    const int co = cog * 8 + (tid >> 5), b = tid & 31;
    const float bias = b2[co];
    const float* __restrict__ rp = raw + (size_t)pg * 4096 + co * 32 + b;

    const int k = co * 169 + pg;
    const size_t zidx0 = ((size_t)((k >> 4) * 2 + ((k >> 3) & 1)) * 32 + b) * 8 + (k & 7);

    float v0=0.f,v1=0.f,v2=0.f,v3=0.f, c0=0.f,c1=0.f,c2=0.f,c3=0.f;
    for (int t = 0; t < T_STEPS; ++t) {
        const float* __restrict__ r = rp + (size_t)t * 692224;
        float zm = 0.f;
        { const float inp = 10.f*(r[0]    + bias); const float vd = v0 + 0.1f*(c0-v0);
          const float z = (vd-1.f>0.f)?1.f:0.f; v0 = (z>0.f)?0.f:vd; c0 = 0.8f*c0 + inp;
          zm = fmaxf(zm, z); }
        { const float inp = 10.f*(r[1024] + bias); const float vd = v1 + 0.1f*(c1-v1);
          const float z = (vd-1.f>0.f)?1.f:0.f; v1 = (z>0.f)?0.f:vd; c1 = 0.8f*c1 + inp;
          zm = fmaxf(zm, z); }
        { const float inp = 10.f*(r[2048] + bias); const float vd = v2 + 0.1f*(c2-v2);
          const float z = (vd-1.f>0.f)?1.f:0.f; v2 = (z>0.f)?0.f:vd; c2 = 0.8f*c2 + inp;
          zm = fmaxf(zm, z); }
        { const float inp = 10.f*(r[3072] + bias); const float vd = v3 + 0.1f*(c3-v3);
          const float z = (vd-1.f>0.f)?1.f:0.f; v3 = (z>0.f)?0.f:vd; c3 = 0.8f*c3 + inp;
          zm = fmaxf(zm, z); }
        zb[(size_t)t * 173056 + zidx0] =
            (unsigned short)(__float_as_uint(zm) >> 16);  // bf16 of 0/1 exact
    }
}

// ---------------- K3: FC as MFMA GEMM, no LDS ----------------
__global__ __launch_bounds__(256) void k3_mfma(
    const unsigned short* __restrict__ wf,   // [3][16nt][338ks][32n][16k]
    const unsigned short* __restrict__ zb,   // [32t][338ks][2kh][32b][8k]
    float* __restrict__ part)                // [13][512][1024]
{
    const int wgid = xcd_swz(blockIdx.x, 416);
    const int ntg = wgid / 52, rest = wgid % 52;
    const int kc = rest >> 2, cgg = rest & 3;
    const int tid = threadIdx.x;
    const int w = tid >> 6, l = tid & 63;
    const int nt = ntg * 2 + (w >> 1);
    const int cg = cgg * 2 + (w & 1);
    const int lo5 = l & 31, hi1 = l >> 5;

    const i32x4* __restrict__ wv = (const i32x4*)wf;
    const i32x4* __restrict__ zv = (const i32x4*)zb;

    f32x16 acc0, acc1, acc2, acc3;
    #pragma unroll
    for (int r = 0; r < 16; ++r) { acc0[r]=0.f; acc1[r]=0.f; acc2[r]=0.f; acc3[r]=0.f; }

    const int ks0 = kc * 26;
    #pragma unroll 2
    for (int kk = 0; kk < 26; ++kk) {
        const int ks = ks0 + kk;
        const int ab = (nt * 338 + ks) * 64 + lo5 * 2 + hi1;
        const bf16x8 A0 = __builtin_bit_cast(bf16x8, wv[ab]);
        const bf16x8 A1 = __builtin_bit_cast(bf16x8, wv[ab + 346112]);
        const bf16x8 A2 = __builtin_bit_cast(bf16x8, wv[ab + 692224]);
        const int b0 = (((cg * 4) * 338 + ks) * 2 + hi1) * 32 + lo5;
        const bf16x8 B0 = __builtin_bit_cast(bf16x8, zv[b0]);
        const bf16x8 B1 = __builtin_bit_cast(bf16x8, zv[b0 + 21632]);
        const bf16x8 B2 = __builtin_bit_cast(bf16x8, zv[b0 + 43264]);
        const bf16x8 B3 = __builtin_bit_cast(bf16x8, zv[b0 + 64896]);
        acc0 = __builtin_amdgcn_mfma_f32_32x32x16_bf16(A0, B0, acc0, 0, 0, 0);
        acc1 = __builtin_amdgcn_mfma_f32_32x32x16_bf16(A0, B1, acc1, 0, 0, 0);
        acc2 = __builtin_amdgcn_mfma_f32_32x32x16_bf16(A0, B2, acc2, 0, 0, 0);
        acc3 = __builtin_amdgcn_mfma_f32_32x32x16_bf16(A0, B3, acc3, 0, 0, 0);
        acc0 = __builtin_amdgcn_mfma_f32_32x32x16_bf16(A1, B0, acc0, 0, 0, 0);
        acc1 = __builtin_amdgcn_mfma_f32_32x32x16_bf16(A1, B1, acc1, 0, 0, 0);
        acc2 = __builtin_amdgcn_mfma_f32_32x32x16_bf16(A1, B2, acc2, 0, 0, 0);
        acc3 = __builtin_amdgcn_mfma_f32_32x32x16_bf16(A1, B3, acc3, 0, 0, 0);
        acc0 = __builtin_amdgcn_mfma_f32_32x32x16_bf16(A2, B0, acc0, 0, 0, 0);
        acc1 = __builtin_amdgcn_mfma_f32_32x32x16_bf16(A2, B1, acc1, 0, 0, 0);
        acc2 = __builtin_amdgcn_mfma_f32_32x32x16_bf16(A2, B2, acc2, 0, 0, 0);
        acc3 = __builtin_amdgcn_mfma_f32_32x32x16_bf16(A2, B3, acc3, 0, 0, 0);
    }

    float* __restrict__ pp = part + ((size_t)(kc * 512 + nt * 32)) * 1024 + cg * 128 + lo5;
    #pragma unroll
    for (int r = 0; r < 16; ++r) {
        const int row = (r & 3) + 8 * (r >> 2) + 4 * hi1;
        pp[row * 1024]      = acc0[r];
        pp[row * 1024 + 32] = acc1[r];
        pp[row * 1024 + 64] = acc2[r];
        pp[row * 1024 + 96] = acc3[r];
    }
}

// ---------------- K3b: reduce 13 partials + bias + LIF scan over t ----------------
__global__ __launch_bounds__(256) void k3b_lif(
    const float* __restrict__ part,  // [13][512][1024], col = t*32+b
    const float* __restrict__ fb,
    float* __restrict__ za)          // [32t][500][32]
{
    const int idx = blockIdx.x * 256 + threadIdx.x;
    if (idx >= 16000) return;
    const int n = idx >> 5, b = idx & 31;
    const float bias = fb[n];

    float v = 0.f, cu = 0.f;
    for (int t = 0; t < T_STEPS; ++t) {
        float s = 0.f;
        #pragma unroll
        for (int p = 0; p < 13; ++p)
            s += part[(size_t)p * 524288 + n * 1024 + t * 32 + b];
        s += bias;

        const float vd = v + 0.1f * (cu - v);
        const float id = 0.8f * cu;
        const float z = (vd - 1.0f > 0.0f) ? 1.0f : 0.0f;
        v = (z > 0.f) ? 0.f : vd;
        cu = id + s;
        za[(size_t)t * 16000 + idx] = z;
    }
}

// ---------------- K4: readout dots per (c,t) ----------------
__global__ __launch_bounds__(256) void k4_dot(
    const float* __restrict__ za,
    const float* __restrict__ ow,
    float* __restrict__ dota)
{
    const int c = blockIdx.x, t = blockIdx.y;
    const int tid = threadIdx.x;
    const int b = tid & 31, nc = tid >> 5;
    const float* __restrict__ wr = ow + c * 500;
    const float* __restrict__ zt = za + (size_t)t * 16000;

    float acc = 0.f;
    for (int j = 0; j < 63; ++j) {
        const int n = nc * 63 + j;
        if (n < 500) acc = fmaf(zt[n * 32 + b], wr[n], acc);
    }

    __shared__ float red[256];
    red[tid] = acc;
    __syncthreads();
    if (tid < 32) {
        float dot = 0.f;
        #pragma unroll
        for (int q = 0; q < 8; ++q) dot += red[q * 32 + tid];
        dota[((size_t)t * 10 + c) * 32 + tid] = dot;
    }
}

// ---------------- K5: LI scan + output ----------------
__global__ __launch_bounds__(320) void k5_li(
    const float* __restrict__ dota,
    float* __restrict__ outp)
{
    const int tid = threadIdx.x;
    if (tid >= 320) return;
    const int c = tid / 32, b = tid & 31;

    float vo = 0.f, io = 0.f;
    for (int t = 0; t < T_STEPS; ++t) {
        const float vout = vo + 0.1f * (io - vo);
        outp[t * 320 + b * 10 + c] = vout;
        vo = vout;
        io = 0.8f * io + dota[(t * 10 + c) * 32 + b];
    }
}

extern "C" void kernel_launch(void* const* d_in, const int* in_sizes, int n_in,
                              void* d_out, int out_size, void* d_ws, size_t ws_size,
                              hipStream_t stream) {
    const float* x  = (const float*)d_in[0];
    const float* w1 = (const float*)d_in[1];
    const float* b1 = (const float*)d_in[2];
    const float* w2 = (const float*)d_in[3];
    const float* b2 = (const float*)d_in[4];
    const float* fw = (const float*)d_in[5];
    const float* fb = (const float*)d_in[6];
    const float* ow = (const float*)d_in[7];
    float* out = (float*)d_out;
    float* ws = (float*)d_ws;

    size_t off = 0;
    float* zp1a = ws + off; off += 14745600;  // zp1c packed; zb overlay after k2a
    float* za   = ws + off; off += 512000;
    float* dota = ws + off; off += 10240;
    unsigned short* wsplit = (unsigned short*)(ws + off); off += 19200;
    float* wfbuf = ws + off; off += 4153344;  // wf: 8.3M u16 (own buffer: written in prep, before k1)
    float* big  = ws + off; off += 22151168;  // union: xT(4.2M)/conv2raw(22.2M)/part(6.8M)
    // ~166 MB total; every region fully written before read.

    float* xT       = big;
    float* conv2raw = big;
    float* part     = big;
    unsigned short* zp1c16 = (unsigned short*)zp1a;  // [32t][2][900][4p][32b] packed
    unsigned short* zb = (unsigned short*)zp1a;      // overlay, zp1c dead after k2a
    unsigned short* wf = (unsigned short*)wfbuf;

    k_prep   <<<2774, 256, 0, stream>>>(x, xT, w2, wsplit, fw, wf);
    k1_conv1 <<<900, 256, 0, stream>>>(xT, w1, b1, zp1c16);
    k2a_mfma <<<1352, 256, 0, stream>>>((const unsigned*)zp1c16, wsplit, conv2raw);
    k2b_lifpool<<<676, 256, 0, stream>>>(conv2raw, b2, zb);   // zp1c dead after k2a
    k3_mfma  <<<416, 256, 0, stream>>>(wf, zb, part);
    k3b_lif  <<<63, 256, 0, stream>>>(part, fb, za);
    k4_dot   <<<dim3(10, 32), 256, 0, stream>>>(za, ow, dota);
    k5_li    <<<1, 320, 0, stream>>>(dota, out);
}

// Round 18
// 211.241 us; speedup vs baseline: 1.1197x; 1.1197x over previous
//
#include <hip/hip_runtime.h>

// SNN: v_dec = v + 0.1*(i - v); i_dec = 0.8*i; spike if v_dec > 1.0
// v' = spike ? 0 : v_dec; i' = i_dec + input.

#define T_STEPS 32

typedef __bf16 bf16x8 __attribute__((ext_vector_type(8)));
typedef float f32x16 __attribute__((ext_vector_type(16)));
typedef int i32x4 __attribute__((ext_vector_type(4)));

// Bijective XCD-chunked block swizzle (m204).
__device__ __forceinline__ int xcd_swz(int orig, int nwg) {
    const int q = nwg >> 3, r = nwg & 7;
    const int xcd = orig & 7, idx = orig >> 3;
    return (xcd < r ? xcd * (q + 1) : r * (q + 1) + (xcd - r) * q) + idx;
}

// ---------------- K_prep: fused {x-transpose, conv2-wsplit, fc-wsplit} ----------------
__global__ __launch_bounds__(256) void k_prep(
    const float* __restrict__ x,  float* __restrict__ xT,
    const float* __restrict__ w2, unsigned short* __restrict__ wsplit,
    const float* __restrict__ fw, unsigned short* __restrict__ wf)
{
    __shared__ float tile[32][65];
    const int bid = blockIdx.x;
    const int tid = threadIdx.x;

    if (bid < 2048) {
        const int y = bid & 63, t = bid >> 6;
        const int lx = tid & 63, bg = tid >> 6;
        #pragma unroll
        for (int p = 0; p < 8; ++p) {
            const int b = bg + p * 4;
            tile[b][lx] = x[((size_t)(t * 32 + b) * 64 + y) * 64 + lx];
        }
        __syncthreads();
        const int wb = tid & 31, xg = tid >> 5;
        #pragma unroll
        for (int p = 0; p < 8; ++p) {
            const int xx = xg + p * 8;
            xT[((size_t)(t * 64 + y) * 64 + xx) * 32 + wb] = tile[wb][xx];
        }
    } else if (bid < 2098) {
        const int i = (bid - 2048) * 256 + tid;
        if (i < 12800) {
            const int co = i / 400, rest = i % 400;
            const int ci = rest / 25, tap = rest % 25;
            const float w = w2[i];
            const unsigned wb = __float_as_uint(w);
            const unsigned hi = wb & 0xFFFF0000u;
            const float r1 = w - __uint_as_float(hi);
            const unsigned mid = __float_as_uint(r1) & 0xFFFF0000u;
            const float r2 = r1 - __uint_as_float(mid);
            const unsigned lo = __float_as_uint(r2) & 0xFFFF0000u;
            const int base = (tap * 32 + co) * 16 + ci;
            wsplit[base]         = (unsigned short)(hi >> 16);
            wsplit[12800 + base] = (unsigned short)(mid >> 16);
            wsplit[25600 + base] = (unsigned short)(lo >> 16);
        }
    } else {
        const int gid = (bid - 2098) * 256 + tid;   // 173056 total
        const int l = gid & 31;
        const int ks = (gid >> 5) % 338;
        const int nt = gid / 10816;
        const int n = nt * 32 + l;

        unsigned hipk[8], midpk[8], lopk[8];
        #pragma unroll
        for (int p = 0; p < 8; ++p) {
            unsigned h[2], m[2], o[2];
            #pragma unroll
            for (int e = 0; e < 2; ++e) {
                const float w = (n < 500) ? fw[(size_t)n * 5408 + ks * 16 + 2 * p + e] : 0.f;
                const unsigned wb = __float_as_uint(w);
                const unsigned hi = wb & 0xFFFF0000u;
                const float r1 = w - __uint_as_float(hi);
                const unsigned mid = __float_as_uint(r1) & 0xFFFF0000u;
                const float r2 = r1 - __uint_as_float(mid);
                h[e] = hi >> 16; m[e] = mid >> 16; o[e] = __float_as_uint(r2) >> 16;
            }
            hipk[p]  = h[0] | (h[1] << 16);
            midpk[p] = m[0] | (m[1] << 16);
            lopk[p]  = o[0] | (o[1] << 16);
        }

        i32x4* __restrict__ wv = (i32x4*)wf;
        const int base = (nt * 338 + ks) * 64 + l * 2;  // i32x4 units; sp stride 346112
        i32x4 a, bq;
        a[0]=(int)hipk[0];a[1]=(int)hipk[1];a[2]=(int)hipk[2];a[3]=(int)hipk[3];
        bq[0]=(int)hipk[4];bq[1]=(int)hipk[5];bq[2]=(int)hipk[6];bq[3]=(int)hipk[7];
        wv[base] = a; wv[base + 1] = bq;
        a[0]=(int)midpk[0];a[1]=(int)midpk[1];a[2]=(int)midpk[2];a[3]=(int)midpk[3];
        bq[0]=(int)midpk[4];bq[1]=(int)midpk[5];bq[2]=(int)midpk[6];bq[3]=(int)midpk[7];
        wv[base + 346112] = a; wv[base + 346113] = bq;
        a[0]=(int)lopk[0];a[1]=(int)lopk[1];a[2]=(int)lopk[2];a[3]=(int)lopk[3];
        bq[0]=(int)lopk[4];bq[1]=(int)lopk[5];bq[2]=(int)lopk[6];bq[3]=(int)lopk[7];
        wv[base + 692224] = a; wv[base + 692225] = bq;
    }
}

// ---------------- K1: conv1 (1->16) + LIF + pool, ALL timesteps (R16 65us version) ----
// grid 900 (pos XCD-swizzled), block 256 = 32 b x 8 slots (2 co per slot).
// Pair layout [8tt][18p][32b][2]: 2-way bank aliasing (free), 18 ds_read_b64/t.
// 8-timestep chunked staging, 8 barriers. VGPR 84 (occupancy-critical: do NOT
// add prefetch registers — R17's T14 attempt cost 20%->9% occupancy, +25us).
__global__ __launch_bounds__(256) void k1_conv1(
    const float* __restrict__ xT,    // [32t,64,64,32b]
    const float* __restrict__ w1,    // [16,1,5,5]
    const float* __restrict__ b1,    // [16]
    unsigned short* __restrict__ zp1c)
{
    const int pos = xcd_swz(blockIdx.x, 900);
    const int py = pos / 30, px = pos % 30;
    const int y0 = 2 * py, x0 = 2 * px;
    const int tid = threadIdx.x;
    const int b = tid & 31, slot = tid >> 5;

    __shared__ float win2[8 * 18 * 64];   // [8tt][18p][32b][2] = 36 KB

    float wreg[2][25];
    #pragma unroll
    for (int k = 0; k < 25; ++k) {
        wreg[0][k] = w1[slot * 25 + k];
        wreg[1][k] = w1[(slot + 8) * 25 + k];
    }
    const float bias0 = b1[slot], bias1 = b1[slot + 8];

    float v[2][4] = {{0.f,0.f,0.f,0.f},{0.f,0.f,0.f,0.f}};
    float cu[2][4] = {{0.f,0.f,0.f,0.f},{0.f,0.f,0.f,0.f}};

    // u16 idx = t*460800 + half*230400 + pos*256 + (slot>>1)*64 + b*2 + (slot&1)
    const size_t obase = (size_t)pos * 256 + (slot >> 1) * 64 + b * 2 + (slot & 1);

    for (int tp = 0; tp < 4; ++tp) {
        __syncthreads();   // previous chunk's readers done
        for (int i = tid; i < 1152; i += 256) {
            const int tt2 = i / 144;
            const int rem = i - tt2 * 144;
            const int p = rem >> 3, bq = rem & 7;
            const int r = p / 3, cpair = p - r * 3;
            const int b0 = bq * 4;
            const float* __restrict__ s0 = xT +
                ((size_t)((tp * 8 + tt2) * 64 + y0 + r) * 64 + (x0 + 2 * cpair)) * 32 + b0;
            const float4 v0 = *(const float4*)s0;
            const float4 v1 = *(const float4*)(s0 + 32);
            float2* __restrict__ d =
                (float2*)win2 + ((tt2 * 18 + p) * 32 + b0);
            d[0] = make_float2(v0.x, v1.x);
            d[1] = make_float2(v0.y, v1.y);
            d[2] = make_float2(v0.z, v1.z);
            d[3] = make_float2(v0.w, v1.w);
        }
        __syncthreads();   // chunk staged

        for (int tt = 0; tt < 8; ++tt) {
            const int t = tp * 8 + tt;
            float xr[36];
            #pragma unroll
            for (int p = 0; p < 18; ++p) {
                const float2 u = ((const float2*)win2)[(tt * 18 + p) * 32 + b];
                const int r = p / 3, cpair = p - r * 3;
                xr[r * 6 + 2 * cpair]     = u.x;
                xr[r * 6 + 2 * cpair + 1] = u.y;
            }

            float acc0[4] = {0.f, 0.f, 0.f, 0.f};
            float acc1[4] = {0.f, 0.f, 0.f, 0.f};
            #pragma unroll
            for (int ky = 0; ky < 5; ++ky) {
                #pragma unroll
                for (int kx = 0; kx < 5; ++kx) {
                    const int tap = ky * 5 + kx;
                    const float e00 = xr[ky * 6 + kx];
                    const float e01 = xr[ky * 6 + kx + 1];
                    const float e10 = xr[(ky + 1) * 6 + kx];
                    const float e11 = xr[(ky + 1) * 6 + kx + 1];
                    const float w0 = wreg[0][tap];
                    acc0[0] = fmaf(w0, e00, acc0[0]);
                    acc0[1] = fmaf(w0, e01, acc0[1]);
                    acc0[2] = fmaf(w0, e10, acc0[2]);
                    acc0[3] = fmaf(w0, e11, acc0[3]);
                    const float w1v = wreg[1][tap];
                    acc1[0] = fmaf(w1v, e00, acc1[0]);
                    acc1[1] = fmaf(w1v, e01, acc1[1]);
                    acc1[2] = fmaf(w1v, e10, acc1[2]);
                    acc1[3] = fmaf(w1v, e11, acc1[3]);
                }
            }

            #pragma unroll
            for (int half = 0; half < 2; ++half) {
                const float* acc = half ? acc1 : acc0;
                const float bias = half ? bias1 : bias0;
                float zmax = 0.f;
                #pragma unroll
                for (int q = 0; q < 4; ++q) {
                    const float inp = acc[q] + bias;
                    const float vv = v[half][q], curr = cu[half][q];
                    const float vd = vv + 0.1f * (curr - vv);
                    const float id = 0.8f * curr;
                    const float z = (vd - 1.0f > 0.0f) ? 1.0f : 0.0f;
                    v[half][q] = (z > 0.f) ? 0.f : vd;
                    cu[half][q] = id + inp;
                    zmax = fmaxf(zmax, z);
                }
                zp1c[(size_t)t * 460800 + (size_t)half * 230400 + obase] =
                    (unsigned short)(__float_as_uint(zmax) >> 16);  // bf16 of 0/1 exact
            }
        }
    }
}

// ---------------- K2a: conv2 as MFMA GEMM (unfused) ----------------
__global__ __launch_bounds__(256, 2) void k2a_mfma(
    const unsigned* __restrict__ zp1c,       // [32t][2cig][30][30][4p][32b] u32
    const unsigned short* __restrict__ wsplit,
    float* __restrict__ raw)                 // [32t][169pg][4q][32co][32b]
{
    __shared__ i32x4 wlds[4800];  // [3sp][25tap][32co][2cig]
    const int tid = threadIdx.x;
    for (int i = tid; i < 4800; i += 256)
        wlds[i] = ((const i32x4*)wsplit)[i];
    __syncthreads();

    const int w = tid >> 6, l = tid & 63;
    const int task = xcd_swz(blockIdx.x, 1352) * 4 + w;
    const int t = task / 169, pg = task % 169;
    const int py = pg / 13, px = pg % 13;
    const int b = l & 31, cig = l >> 5;
    const int abase = (l & 31) * 2 + cig;

    const unsigned* __restrict__ zt =
        zp1c + (size_t)(t * 2 + cig) * 115200 + ((2 * py) * 30 + 2 * px) * 128 + b;

    f32x16 accA, accB, accC, accD;
    #pragma unroll
    for (int r = 0; r < 16; ++r) { accA[r] = 0.f; accB[r] = 0.f; accC[r] = 0.f; accD[r] = 0.f; }

    #pragma unroll
    for (int wy = 0; wy < 6; ++wy) {
        i32x4 bw[6];
        #pragma unroll
        for (int wx = 0; wx < 6; ++wx) {
            const unsigned* __restrict__ c = zt + (wy * 30 + wx) * 128;
            bw[wx][0] = (int)c[0];
            bw[wx][1] = (int)c[32];
            bw[wx][2] = (int)c[64];
            bw[wx][3] = (int)c[96];
        }
        if (wy <= 4) {
            #pragma unroll
            for (int sp = 0; sp < 3; ++sp) {
                #pragma unroll
                for (int kx = 0; kx < 5; ++kx) {
                    const int tap = wy * 5 + kx;
                    const bf16x8 A = __builtin_bit_cast(bf16x8, wlds[(sp * 25 + tap) * 64 + abase]);
                    accA = __builtin_amdgcn_mfma_f32_32x32x16_bf16(
                        A, __builtin_bit_cast(bf16x8, bw[kx]),     accA, 0, 0, 0);
                    accB = __builtin_amdgcn_mfma_f32_32x32x16_bf16(
                        A, __builtin_bit_cast(bf16x8, bw[kx + 1]), accB, 0, 0, 0);
                }
            }
        }
        if (wy >= 1) {
            #pragma unroll
            for (int sp = 0; sp < 3; ++sp) {
                #pragma unroll
                for (int kx = 0; kx < 5; ++kx) {
                    const int tap = (wy - 1) * 5 + kx;
                    const bf16x8 A = __builtin_bit_cast(bf16x8, wlds[(sp * 25 + tap) * 64 + abase]);
                    accC = __builtin_amdgcn_mfma_f32_32x32x16_bf16(
                        A, __builtin_bit_cast(bf16x8, bw[kx]),     accC, 0, 0, 0);
                    accD = __builtin_amdgcn_mfma_f32_32x32x16_bf16(
                        A, __builtin_bit_cast(bf16x8, bw[kx + 1]), accD, 0, 0, 0);
                }
            }
        }
    }

    float* __restrict__ rp = raw + (size_t)(t * 169 + pg) * 4096 + b;
    const int hi = l >> 5;
    #pragma unroll
    for (int r = 0; r < 16; ++r) {
        const int row = (r & 3) + 8 * (r >> 2) + 4 * hi;
        rp[row * 32]        = accA[r];
        rp[1024 + row * 32] = accB[r];
        rp[2048 + row * 32] = accC[r];
        rp[3072 + row * 32] = accD[r];
    }
}

// ---------------- K2b: LIF + pool scan over t; writes packed bf16 zb directly ----------
__global__ __launch_bounds__(256) void k2b_lifpool(
    const float* __restrict__ raw,   // [32t][169pg][4q][32co][32b]
    const float* __restrict__ b2,
    unsigned short* __restrict__ zb) // [32t][338ks][2kh][32b][8k8]
{
    const int bid = blockIdx.x;
    const int pg = bid >> 2, cog = bid & 3;
    const int tid = threadIdx.x;
    const int co = cog * 8 + (tid >> 5), b = tid & 31;
    const float bias = b2[co];
    const float* __restrict__ rp = raw + (size_t)pg * 4096 + co * 32 + b;

    const int k = co * 169 + pg;
    const size_t zidx0 = ((size_t)((k >> 4) * 2 + ((k >> 3) & 1)) * 32 + b) * 8 + (k & 7);

    float v0=0.f,v1=0.f,v2=0.f,v3=0.f, c0=0.f,c1=0.f,c2=0.f,c3=0.f;
    for (int t = 0; t < T_STEPS; ++t) {
        const float* __restrict__ r = rp + (size_t)t * 692224;
        float zm = 0.f;
        { const float inp = 10.f*(r[0]    + bias); const float vd = v0 + 0.1f*(c0-v0);
          const float z = (vd-1.f>0.f)?1.f:0.f; v0 = (z>0.f)?0.f:vd; c0 = 0.8f*c0 + inp;
          zm = fmaxf(zm, z); }
        { const float inp = 10.f*(r[1024] + bias); const float vd = v1 + 0.1f*(c1-v1);
          const float z = (vd-1.f>0.f)?1.f:0.f; v1 = (z>0.f)?0.f:vd; c1 = 0.8f*c1 + inp;
          zm = fmaxf(zm, z); }
        { const float inp = 10.f*(r[2048] + bias); const float vd = v2 + 0.1f*(c2-v2);
          const float z = (vd-1.f>0.f)?1.f:0.f; v2 = (z>0.f)?0.f:vd; c2 = 0.8f*c2 + inp;
          zm = fmaxf(zm, z); }
        { const float inp = 10.f*(r[3072] + bias); const float vd = v3 + 0.1f*(c3-v3);
          const float z = (vd-1.f>0.f)?1.f:0.f; v3 = (z>0.f)?0.f:vd; c3 = 0.8f*c3 + inp;
          zm = fmaxf(zm, z); }
        zb[(size_t)t * 173056 + zidx0] =
            (unsigned short)(__float_as_uint(zm) >> 16);  // bf16 of 0/1 exact
    }
}

// ---------------- K3: FC as MFMA GEMM, no LDS ----------------
__global__ __launch_bounds__(256) void k3_mfma(
    const unsigned short* __restrict__ wf,   // [3][16nt][338ks][32n][16k]
    const unsigned short* __restrict__ zb,   // [32t][338ks][2kh][32b][8k]
    float* __restrict__ part)                // [13][512][1024]
{
    const int wgid = xcd_swz(blockIdx.x, 416);
    const int ntg = wgid / 52, rest = wgid % 52;
    const int kc = rest >> 2, cgg = rest & 3;
    const int tid = threadIdx.x;
    const int w = tid >> 6, l = tid & 63;
    const int nt = ntg * 2 + (w >> 1);
    const int cg = cgg * 2 + (w & 1);
    const int lo5 = l & 31, hi1 = l >> 5;

    const i32x4* __restrict__ wv = (const i32x4*)wf;
    const i32x4* __restrict__ zv = (const i32x4*)zb;

    f32x16 acc0, acc1, acc2, acc3;
    #pragma unroll
    for (int r = 0; r < 16; ++r) { acc0[r]=0.f; acc1[r]=0.f; acc2[r]=0.f; acc3[r]=0.f; }

    const int ks0 = kc * 26;
    #pragma unroll 2
    for (int kk = 0; kk < 26; ++kk) {
        const int ks = ks0 + kk;
        const int ab = (nt * 338 + ks) * 64 + lo5 * 2 + hi1;
        const bf16x8 A0 = __builtin_bit_cast(bf16x8, wv[ab]);
        const bf16x8 A1 = __builtin_bit_cast(bf16x8, wv[ab + 346112]);
        const bf16x8 A2 = __builtin_bit_cast(bf16x8, wv[ab + 692224]);
        const int b0 = (((cg * 4) * 338 + ks) * 2 + hi1) * 32 + lo5;
        const bf16x8 B0 = __builtin_bit_cast(bf16x8, zv[b0]);
        const bf16x8 B1 = __builtin_bit_cast(bf16x8, zv[b0 + 21632]);
        const bf16x8 B2 = __builtin_bit_cast(bf16x8, zv[b0 + 43264]);
        const bf16x8 B3 = __builtin_bit_cast(bf16x8, zv[b0 + 64896]);
        acc0 = __builtin_amdgcn_mfma_f32_32x32x16_bf16(A0, B0, acc0, 0, 0, 0);
        acc1 = __builtin_amdgcn_mfma_f32_32x32x16_bf16(A0, B1, acc1, 0, 0, 0);
        acc2 = __builtin_amdgcn_mfma_f32_32x32x16_bf16(A0, B2, acc2, 0, 0, 0);
        acc3 = __builtin_amdgcn_mfma_f32_32x32x16_bf16(A0, B3, acc3, 0, 0, 0);
        acc0 = __builtin_amdgcn_mfma_f32_32x32x16_bf16(A1, B0, acc0, 0, 0, 0);
        acc1 = __builtin_amdgcn_mfma_f32_32x32x16_bf16(A1, B1, acc1, 0, 0, 0);
        acc2 = __builtin_amdgcn_mfma_f32_32x32x16_bf16(A1, B2, acc2, 0, 0, 0);
        acc3 = __builtin_amdgcn_mfma_f32_32x32x16_bf16(A1, B3, acc3, 0, 0, 0);
        acc0 = __builtin_amdgcn_mfma_f32_32x32x16_bf16(A2, B0, acc0, 0, 0, 0);
        acc1 = __builtin_amdgcn_mfma_f32_32x32x16_bf16(A2, B1, acc1, 0, 0, 0);
        acc2 = __builtin_amdgcn_mfma_f32_32x32x16_bf16(A2, B2, acc2, 0, 0, 0);
        acc3 = __builtin_amdgcn_mfma_f32_32x32x16_bf16(A2, B3, acc3, 0, 0, 0);
    }

    float* __restrict__ pp = part + ((size_t)(kc * 512 + nt * 32)) * 1024 + cg * 128 + lo5;
    #pragma unroll
    for (int r = 0; r < 16; ++r) {
        const int row = (r & 3) + 8 * (r >> 2) + 4 * hi1;
        pp[row * 1024]      = acc0[r];
        pp[row * 1024 + 32] = acc1[r];
        pp[row * 1024 + 64] = acc2[r];
        pp[row * 1024 + 96] = acc3[r];
    }
}

// ---------------- K3b: reduce 13 partials + bias + LIF scan over t ----------------
__global__ __launch_bounds__(256) void k3b_lif(
    const float* __restrict__ part,  // [13][512][1024], col = t*32+b
    const float* __restrict__ fb,
    float* __restrict__ za)          // [32t][500][32]
{
    const int idx = blockIdx.x * 256 + threadIdx.x;
    if (idx >= 16000) return;
    const int n = idx >> 5, b = idx & 31;
    const float bias = fb[n];

    float v = 0.f, cu = 0.f;
    for (int t = 0; t < T_STEPS; ++t) {
        float s = 0.f;
        #pragma unroll
        for (int p = 0; p < 13; ++p)
            s += part[(size_t)p * 524288 + n * 1024 + t * 32 + b];
        s += bias;

        const float vd = v + 0.1f * (cu - v);
        const float id = 0.8f * cu;
        const float z = (vd - 1.0f > 0.0f) ? 1.0f : 0.0f;
        v = (z > 0.f) ? 0.f : vd;
        cu = id + s;
        za[(size_t)t * 16000 + idx] = z;
    }
}

// ---------------- K4: readout dots per (c,t) ----------------
__global__ __launch_bounds__(256) void k4_dot(
    const float* __restrict__ za,
    const float* __restrict__ ow,
    float* __restrict__ dota)
{
    const int c = blockIdx.x, t = blockIdx.y;
    const int tid = threadIdx.x;
    const int b = tid & 31, nc = tid >> 5;
    const float* __restrict__ wr = ow + c * 500;
    const float* __restrict__ zt = za + (size_t)t * 16000;

    float acc = 0.f;
    for (int j = 0; j < 63; ++j) {
        const int n = nc * 63 + j;
        if (n < 500) acc = fmaf(zt[n * 32 + b], wr[n], acc);
    }

    __shared__ float red[256];
    red[tid] = acc;
    __syncthreads();
    if (tid < 32) {
        float dot = 0.f;
        #pragma unroll
        for (int q = 0; q < 8; ++q) dot += red[q * 32 + tid];
        dota[((size_t)t * 10 + c) * 32 + tid] = dot;
    }
}

// ---------------- K5: LI scan + output ----------------
__global__ __launch_bounds__(320) void k5_li(
    const float* __restrict__ dota,
    float* __restrict__ outp)
{
    const int tid = threadIdx.x;
    if (tid >= 320) return;
    const int c = tid / 32, b = tid & 31;

    float vo = 0.f, io = 0.f;
    for (int t = 0; t < T_STEPS; ++t) {
        const float vout = vo + 0.1f * (io - vo);
        outp[t * 320 + b * 10 + c] = vout;
        vo = vout;
        io = 0.8f * io + dota[(t * 10 + c) * 32 + b];
    }
}

extern "C" void kernel_launch(void* const* d_in, const int* in_sizes, int n_in,
                              void* d_out, int out_size, void* d_ws, size_t ws_size,
                              hipStream_t stream) {
    const float* x  = (const float*)d_in[0];
    const float* w1 = (const float*)d_in[1];
    const float* b1 = (const float*)d_in[2];
    const float* w2 = (const float*)d_in[3];
    const float* b2 = (const float*)d_in[4];
    const float* fw = (const float*)d_in[5];
    const float* fb = (const float*)d_in[6];
    const float* ow = (const float*)d_in[7];
    float* out = (float*)d_out;
    float* ws = (float*)d_ws;

    size_t off = 0;
    float* zp1a = ws + off; off += 14745600;  // zp1c packed; zb overlay after k2a
    float* za   = ws + off; off += 512000;
    float* dota = ws + off; off += 10240;
    unsigned short* wsplit = (unsigned short*)(ws + off); off += 19200;
    float* wfbuf = ws + off; off += 4153344;  // wf: 8.3M u16 (written in prep, before k1)
    float* big  = ws + off; off += 22151168;  // union: xT(4.2M)/conv2raw(22.2M)/part(6.8M)
    // ~166 MB total; every region fully written before read.

    float* xT       = big;
    float* conv2raw = big;
    float* part     = big;
    unsigned short* zp1c16 = (unsigned short*)zp1a;  // [32t][2][900][4p][32b] packed
    unsigned short* zb = (unsigned short*)zp1a;      // overlay, zp1c dead after k2a
    unsigned short* wf = (unsigned short*)wfbuf;

    k_prep   <<<2774, 256, 0, stream>>>(x, xT, w2, wsplit, fw, wf);
    k1_conv1 <<<900, 256, 0, stream>>>(xT, w1, b1, zp1c16);
    k2a_mfma <<<1352, 256, 0, stream>>>((const unsigned*)zp1c16, wsplit, conv2raw);
    k2b_lifpool<<<676, 256, 0, stream>>>(conv2raw, b2, zb);   // zp1c dead after k2a
    k3_mfma  <<<416, 256, 0, stream>>>(wf, zb, part);
    k3b_lif  <<<63, 256, 0, stream>>>(part, fb, za);
    k4_dot   <<<dim3(10, 32), 256, 0, stream>>>(za, ow, dota);
    k5_li    <<<1, 320, 0, stream>>>(dota, out);
}

// Round 19
// 207.341 us; speedup vs baseline: 1.1408x; 1.0188x over previous
//
#include <hip/hip_runtime.h>

// SNN: v_dec = v + 0.1*(i - v); i_dec = 0.8*i; spike if v_dec > 1.0
// v' = spike ? 0 : v_dec; i' = i_dec + input.

#define T_STEPS 32

typedef __bf16 bf16x8 __attribute__((ext_vector_type(8)));
typedef float f32x16 __attribute__((ext_vector_type(16)));
typedef int i32x4 __attribute__((ext_vector_type(4)));

// Bijective XCD-chunked block swizzle (m204).
__device__ __forceinline__ int xcd_swz(int orig, int nwg) {
    const int q = nwg >> 3, r = nwg & 7;
    const int xcd = orig & 7, idx = orig >> 3;
    return (xcd < r ? xcd * (q + 1) : r * (q + 1) + (xcd - r) * q) + idx;
}

// ---------------- K_prep: fused {x-transpose, conv2-wsplit, fc-wsplit} ----------------
__global__ __launch_bounds__(256) void k_prep(
    const float* __restrict__ x,  float* __restrict__ xT,
    const float* __restrict__ w2, unsigned short* __restrict__ wsplit,
    const float* __restrict__ fw, unsigned short* __restrict__ wf)
{
    __shared__ float tile[32][65];
    const int bid = blockIdx.x;
    const int tid = threadIdx.x;

    if (bid < 2048) {
        const int y = bid & 63, t = bid >> 6;
        const int lx = tid & 63, bg = tid >> 6;
        #pragma unroll
        for (int p = 0; p < 8; ++p) {
            const int b = bg + p * 4;
            tile[b][lx] = x[((size_t)(t * 32 + b) * 64 + y) * 64 + lx];
        }
        __syncthreads();
        const int wb = tid & 31, xg = tid >> 5;
        #pragma unroll
        for (int p = 0; p < 8; ++p) {
            const int xx = xg + p * 8;
            xT[((size_t)(t * 64 + y) * 64 + xx) * 32 + wb] = tile[wb][xx];
        }
    } else if (bid < 2098) {
        const int i = (bid - 2048) * 256 + tid;
        if (i < 12800) {
            const int co = i / 400, rest = i % 400;
            const int ci = rest / 25, tap = rest % 25;
            const float w = w2[i];
            const unsigned wb = __float_as_uint(w);
            const unsigned hi = wb & 0xFFFF0000u;
            const float r1 = w - __uint_as_float(hi);
            const unsigned mid = __float_as_uint(r1) & 0xFFFF0000u;
            const float r2 = r1 - __uint_as_float(mid);
            const unsigned lo = __float_as_uint(r2) & 0xFFFF0000u;
            const int base = (tap * 32 + co) * 16 + ci;
            wsplit[base]         = (unsigned short)(hi >> 16);
            wsplit[12800 + base] = (unsigned short)(mid >> 16);
            wsplit[25600 + base] = (unsigned short)(lo >> 16);
        }
    } else {
        const int gid = (bid - 2098) * 256 + tid;   // 173056 total
        const int l = gid & 31;
        const int ks = (gid >> 5) % 338;
        const int nt = gid / 10816;
        const int n = nt * 32 + l;

        unsigned hipk[8], midpk[8], lopk[8];
        #pragma unroll
        for (int p = 0; p < 8; ++p) {
            unsigned h[2], m[2], o[2];
            #pragma unroll
            for (int e = 0; e < 2; ++e) {
                const float w = (n < 500) ? fw[(size_t)n * 5408 + ks * 16 + 2 * p + e] : 0.f;
                const unsigned wb = __float_as_uint(w);
                const unsigned hi = wb & 0xFFFF0000u;
                const float r1 = w - __uint_as_float(hi);
                const unsigned mid = __float_as_uint(r1) & 0xFFFF0000u;
                const float r2 = r1 - __uint_as_float(mid);
                h[e] = hi >> 16; m[e] = mid >> 16; o[e] = __float_as_uint(r2) >> 16;
            }
            hipk[p]  = h[0] | (h[1] << 16);
            midpk[p] = m[0] | (m[1] << 16);
            lopk[p]  = o[0] | (o[1] << 16);
        }

        i32x4* __restrict__ wv = (i32x4*)wf;
        const int base = (nt * 338 + ks) * 64 + l * 2;  // i32x4 units; sp stride 346112
        i32x4 a, bq;
        a[0]=(int)hipk[0];a[1]=(int)hipk[1];a[2]=(int)hipk[2];a[3]=(int)hipk[3];
        bq[0]=(int)hipk[4];bq[1]=(int)hipk[5];bq[2]=(int)hipk[6];bq[3]=(int)hipk[7];
        wv[base] = a; wv[base + 1] = bq;
        a[0]=(int)midpk[0];a[1]=(int)midpk[1];a[2]=(int)midpk[2];a[3]=(int)midpk[3];
        bq[0]=(int)midpk[4];bq[1]=(int)midpk[5];bq[2]=(int)midpk[6];bq[3]=(int)midpk[7];
        wv[base + 346112] = a; wv[base + 346113] = bq;
        a[0]=(int)lopk[0];a[1]=(int)lopk[1];a[2]=(int)lopk[2];a[3]=(int)lopk[3];
        bq[0]=(int)lopk[4];bq[1]=(int)lopk[5];bq[2]=(int)lopk[6];bq[3]=(int)lopk[7];
        wv[base + 692224] = a; wv[base + 692225] = bq;
    }
}

// ---------------- K1: conv1 (1->16) + LIF + pool, ALL timesteps (65us verified) ----
// grid 900 (pos XCD-swizzled), block 256 = 32 b x 8 slots (2 co per slot).
// Pair layout [8tt][18p][32b][2]: 2-way bank aliasing (free), 18 ds_read_b64/t.
// 8-timestep chunked staging, 8 barriers. VGPR 84 (occupancy-critical).
__global__ __launch_bounds__(256) void k1_conv1(
    const float* __restrict__ xT,    // [32t,64,64,32b]
    const float* __restrict__ w1,    // [16,1,5,5]
    const float* __restrict__ b1,    // [16]
    unsigned short* __restrict__ zp1c)
{
    const int pos = xcd_swz(blockIdx.x, 900);
    const int py = pos / 30, px = pos % 30;
    const int y0 = 2 * py, x0 = 2 * px;
    const int tid = threadIdx.x;
    const int b = tid & 31, slot = tid >> 5;

    __shared__ float win2[8 * 18 * 64];   // [8tt][18p][32b][2] = 36 KB

    float wreg[2][25];
    #pragma unroll
    for (int k = 0; k < 25; ++k) {
        wreg[0][k] = w1[slot * 25 + k];
        wreg[1][k] = w1[(slot + 8) * 25 + k];
    }
    const float bias0 = b1[slot], bias1 = b1[slot + 8];

    float v[2][4] = {{0.f,0.f,0.f,0.f},{0.f,0.f,0.f,0.f}};
    float cu[2][4] = {{0.f,0.f,0.f,0.f},{0.f,0.f,0.f,0.f}};

    // u16 idx = t*460800 + half*230400 + pos*256 + (slot>>1)*64 + b*2 + (slot&1)
    const size_t obase = (size_t)pos * 256 + (slot >> 1) * 64 + b * 2 + (slot & 1);

    for (int tp = 0; tp < 4; ++tp) {
        __syncthreads();   // previous chunk's readers done
        for (int i = tid; i < 1152; i += 256) {
            const int tt2 = i / 144;
            const int rem = i - tt2 * 144;
            const int p = rem >> 3, bq = rem & 7;
            const int r = p / 3, cpair = p - r * 3;
            const int b0 = bq * 4;
            const float* __restrict__ s0 = xT +
                ((size_t)((tp * 8 + tt2) * 64 + y0 + r) * 64 + (x0 + 2 * cpair)) * 32 + b0;
            const float4 v0 = *(const float4*)s0;
            const float4 v1 = *(const float4*)(s0 + 32);
            float2* __restrict__ d =
                (float2*)win2 + ((tt2 * 18 + p) * 32 + b0);
            d[0] = make_float2(v0.x, v1.x);
            d[1] = make_float2(v0.y, v1.y);
            d[2] = make_float2(v0.z, v1.z);
            d[3] = make_float2(v0.w, v1.w);
        }
        __syncthreads();   // chunk staged

        for (int tt = 0; tt < 8; ++tt) {
            const int t = tp * 8 + tt;
            float xr[36];
            #pragma unroll
            for (int p = 0; p < 18; ++p) {
                const float2 u = ((const float2*)win2)[(tt * 18 + p) * 32 + b];
                const int r = p / 3, cpair = p - r * 3;
                xr[r * 6 + 2 * cpair]     = u.x;
                xr[r * 6 + 2 * cpair + 1] = u.y;
            }

            float acc0[4] = {0.f, 0.f, 0.f, 0.f};
            float acc1[4] = {0.f, 0.f, 0.f, 0.f};
            #pragma unroll
            for (int ky = 0; ky < 5; ++ky) {
                #pragma unroll
                for (int kx = 0; kx < 5; ++kx) {
                    const int tap = ky * 5 + kx;
                    const float e00 = xr[ky * 6 + kx];
                    const float e01 = xr[ky * 6 + kx + 1];
                    const float e10 = xr[(ky + 1) * 6 + kx];
                    const float e11 = xr[(ky + 1) * 6 + kx + 1];
                    const float w0 = wreg[0][tap];
                    acc0[0] = fmaf(w0, e00, acc0[0]);
                    acc0[1] = fmaf(w0, e01, acc0[1]);
                    acc0[2] = fmaf(w0, e10, acc0[2]);
                    acc0[3] = fmaf(w0, e11, acc0[3]);
                    const float w1v = wreg[1][tap];
                    acc1[0] = fmaf(w1v, e00, acc1[0]);
                    acc1[1] = fmaf(w1v, e01, acc1[1]);
                    acc1[2] = fmaf(w1v, e10, acc1[2]);
                    acc1[3] = fmaf(w1v, e11, acc1[3]);
                }
            }

            #pragma unroll
            for (int half = 0; half < 2; ++half) {
                const float* acc = half ? acc1 : acc0;
                const float bias = half ? bias1 : bias0;
                float zmax = 0.f;
                #pragma unroll
                for (int q = 0; q < 4; ++q) {
                    const float inp = acc[q] + bias;
                    const float vv = v[half][q], curr = cu[half][q];
                    const float vd = vv + 0.1f * (curr - vv);
                    const float id = 0.8f * curr;
                    const float z = (vd - 1.0f > 0.0f) ? 1.0f : 0.0f;
                    v[half][q] = (z > 0.f) ? 0.f : vd;
                    cu[half][q] = id + inp;
                    zmax = fmaxf(zmax, z);
                }
                zp1c[(size_t)t * 460800 + (size_t)half * 230400 + obase] =
                    (unsigned short)(__float_as_uint(zmax) >> 16);  // bf16 of 0/1 exact
            }
        }
    }
}

// ---------------- K2a: conv2 as MFMA GEMM (unfused) ----------------
// 1 wave per block, grid 5408, NO LDS: A-frags read directly from global wsplit
// (76.8KB chip-wide, L1/L2 broadcast). Removes the 75KB LDS mirror that capped
// occupancy at 2 blocks/CU and the 101MB per-block preload traffic.
__global__ __launch_bounds__(64) void k2a_mfma(
    const unsigned* __restrict__ zp1c,       // [32t][2cig][30][30][4p][32b] u32
    const unsigned short* __restrict__ wsplit,
    float* __restrict__ raw)                 // [32t][169pg][4q][32co][32b]
{
    const int l = threadIdx.x;
    const int task = xcd_swz(blockIdx.x, 5408);
    const int t = task / 169, pg = task % 169;
    const int py = pg / 13, px = pg % 13;
    const int b = l & 31, cig = l >> 5;
    const int abase = (l & 31) * 2 + cig;

    const i32x4* __restrict__ wv = (const i32x4*)wsplit;

    const unsigned* __restrict__ zt =
        zp1c + (size_t)(t * 2 + cig) * 115200 + ((2 * py) * 30 + 2 * px) * 128 + b;

    f32x16 accA, accB, accC, accD;
    #pragma unroll
    for (int r = 0; r < 16; ++r) { accA[r] = 0.f; accB[r] = 0.f; accC[r] = 0.f; accD[r] = 0.f; }

    #pragma unroll
    for (int wy = 0; wy < 6; ++wy) {
        i32x4 bw[6];
        #pragma unroll
        for (int wx = 0; wx < 6; ++wx) {
            const unsigned* __restrict__ c = zt + (wy * 30 + wx) * 128;
            bw[wx][0] = (int)c[0];
            bw[wx][1] = (int)c[32];
            bw[wx][2] = (int)c[64];
            bw[wx][3] = (int)c[96];
        }
        if (wy <= 4) {
            #pragma unroll
            for (int sp = 0; sp < 3; ++sp) {
                #pragma unroll
                for (int kx = 0; kx < 5; ++kx) {
                    const int tap = wy * 5 + kx;
                    const bf16x8 A = __builtin_bit_cast(bf16x8, wv[(sp * 25 + tap) * 64 + abase]);
                    accA = __builtin_amdgcn_mfma_f32_32x32x16_bf16(
                        A, __builtin_bit_cast(bf16x8, bw[kx]),     accA, 0, 0, 0);
                    accB = __builtin_amdgcn_mfma_f32_32x32x16_bf16(
                        A, __builtin_bit_cast(bf16x8, bw[kx + 1]), accB, 0, 0, 0);
                }
            }
        }
        if (wy >= 1) {
            #pragma unroll
            for (int sp = 0; sp < 3; ++sp) {
                #pragma unroll
                for (int kx = 0; kx < 5; ++kx) {
                    const int tap = (wy - 1) * 5 + kx;
                    const bf16x8 A = __builtin_bit_cast(bf16x8, wv[(sp * 25 + tap) * 64 + abase]);
                    accC = __builtin_amdgcn_mfma_f32_32x32x16_bf16(
                        A, __builtin_bit_cast(bf16x8, bw[kx]),     accC, 0, 0, 0);
                    accD = __builtin_amdgcn_mfma_f32_32x32x16_bf16(
                        A, __builtin_bit_cast(bf16x8, bw[kx + 1]), accD, 0, 0, 0);
                }
            }
        }
    }

    float* __restrict__ rp = raw + (size_t)(t * 169 + pg) * 4096 + b;
    const int hi = l >> 5;
    #pragma unroll
    for (int r = 0; r < 16; ++r) {
        const int row = (r & 3) + 8 * (r >> 2) + 4 * hi;
        rp[row * 32]        = accA[r];
        rp[1024 + row * 32] = accB[r];
        rp[2048 + row * 32] = accC[r];
        rp[3072 + row * 32] = accD[r];
    }
}

// ---------------- K2b: LIF + pool scan over t; writes packed bf16 zb directly ----------
__global__ __launch_bounds__(256) void k2b_lifpool(
    const float* __restrict__ raw,   // [32t][169pg][4q][32co][32b]
    const float* __restrict__ b2,
    unsigned short* __restrict__ zb) // [32t][338ks][2kh][32b][8k8]
{
    const int bid = blockIdx.x;
    const int pg = bid >> 2, cog = bid & 3;
    const int tid = threadIdx.x;
    const int co = cog * 8 + (tid >> 5), b = tid & 31;
    const float bias = b2[co];
    const float* __restrict__ rp = raw + (size_t)pg * 4096 + co * 32 + b;

    const int k = co * 169 + pg;
    const size_t zidx0 = ((size_t)((k >> 4) * 2 + ((k >> 3) & 1)) * 32 + b) * 8 + (k & 7);

    float v0=0.f,v1=0.f,v2=0.f,v3=0.f, c0=0.f,c1=0.f,c2=0.f,c3=0.f;
    for (int t = 0; t < T_STEPS; ++t) {
        const float* __restrict__ r = rp + (size_t)t * 692224;
        float zm = 0.f;
        { const float inp = 10.f*(r[0]    + bias); const float vd = v0 + 0.1f*(c0-v0);
          const float z = (vd-1.f>0.f)?1.f:0.f; v0 = (z>0.f)?0.f:vd; c0 = 0.8f*c0 + inp;
          zm = fmaxf(zm, z); }
        { const float inp = 10.f*(r[1024] + bias); const float vd = v1 + 0.1f*(c1-v1);
          const float z = (vd-1.f>0.f)?1.f:0.f; v1 = (z>0.f)?0.f:vd; c1 = 0.8f*c1 + inp;
          zm = fmaxf(zm, z); }
        { const float inp = 10.f*(r[2048] + bias); const float vd = v2 + 0.1f*(c2-v2);
          const float z = (vd-1.f>0.f)?1.f:0.f; v2 = (z>0.f)?0.f:vd; c2 = 0.8f*c2 + inp;
          zm = fmaxf(zm, z); }
        { const float inp = 10.f*(r[3072] + bias); const float vd = v3 + 0.1f*(c3-v3);
          const float z = (vd-1.f>0.f)?1.f:0.f; v3 = (z>0.f)?0.f:vd; c3 = 0.8f*c3 + inp;
          zm = fmaxf(zm, z); }
        zb[(size_t)t * 173056 + zidx0] =
            (unsigned short)(__float_as_uint(zm) >> 16);  // bf16 of 0/1 exact
    }
}

// ---------------- K3: FC as MFMA GEMM, no LDS ----------------
__global__ __launch_bounds__(256) void k3_mfma(
    const unsigned short* __restrict__ wf,   // [3][16nt][338ks][32n][16k]
    const unsigned short* __restrict__ zb,   // [32t][338ks][2kh][32b][8k]
    float* __restrict__ part)                // [13][512][1024]
{
    const int wgid = xcd_swz(blockIdx.x, 416);
    const int ntg = wgid / 52, rest = wgid % 52;
    const int kc = rest >> 2, cgg = rest & 3;
    const int tid = threadIdx.x;
    const int w = tid >> 6, l = tid & 63;
    const int nt = ntg * 2 + (w >> 1);
    const int cg = cgg * 2 + (w & 1);
    const int lo5 = l & 31, hi1 = l >> 5;

    const i32x4* __restrict__ wv = (const i32x4*)wf;
    const i32x4* __restrict__ zv = (const i32x4*)zb;

    f32x16 acc0, acc1, acc2, acc3;
    #pragma unroll
    for (int r = 0; r < 16; ++r) { acc0[r]=0.f; acc1[r]=0.f; acc2[r]=0.f; acc3[r]=0.f; }

    const int ks0 = kc * 26;
    #pragma unroll 2
    for (int kk = 0; kk < 26; ++kk) {
        const int ks = ks0 + kk;
        const int ab = (nt * 338 + ks) * 64 + lo5 * 2 + hi1;
        const bf16x8 A0 = __builtin_bit_cast(bf16x8, wv[ab]);
        const bf16x8 A1 = __builtin_bit_cast(bf16x8, wv[ab + 346112]);
        const bf16x8 A2 = __builtin_bit_cast(bf16x8, wv[ab + 692224]);
        const int b0 = (((cg * 4) * 338 + ks) * 2 + hi1) * 32 + lo5;
        const bf16x8 B0 = __builtin_bit_cast(bf16x8, zv[b0]);
        const bf16x8 B1 = __builtin_bit_cast(bf16x8, zv[b0 + 21632]);
        const bf16x8 B2 = __builtin_bit_cast(bf16x8, zv[b0 + 43264]);
        const bf16x8 B3 = __builtin_bit_cast(bf16x8, zv[b0 + 64896]);
        acc0 = __builtin_amdgcn_mfma_f32_32x32x16_bf16(A0, B0, acc0, 0, 0, 0);
        acc1 = __builtin_amdgcn_mfma_f32_32x32x16_bf16(A0, B1, acc1, 0, 0, 0);
        acc2 = __builtin_amdgcn_mfma_f32_32x32x16_bf16(A0, B2, acc2, 0, 0, 0);
        acc3 = __builtin_amdgcn_mfma_f32_32x32x16_bf16(A0, B3, acc3, 0, 0, 0);
        acc0 = __builtin_amdgcn_mfma_f32_32x32x16_bf16(A1, B0, acc0, 0, 0, 0);
        acc1 = __builtin_amdgcn_mfma_f32_32x32x16_bf16(A1, B1, acc1, 0, 0, 0);
        acc2 = __builtin_amdgcn_mfma_f32_32x32x16_bf16(A1, B2, acc2, 0, 0, 0);
        acc3 = __builtin_amdgcn_mfma_f32_32x32x16_bf16(A1, B3, acc3, 0, 0, 0);
        acc0 = __builtin_amdgcn_mfma_f32_32x32x16_bf16(A2, B0, acc0, 0, 0, 0);
        acc1 = __builtin_amdgcn_mfma_f32_32x32x16_bf16(A2, B1, acc1, 0, 0, 0);
        acc2 = __builtin_amdgcn_mfma_f32_32x32x16_bf16(A2, B2, acc2, 0, 0, 0);
        acc3 = __builtin_amdgcn_mfma_f32_32x32x16_bf16(A2, B3, acc3, 0, 0, 0);
    }

    float* __restrict__ pp = part + ((size_t)(kc * 512 + nt * 32)) * 1024 + cg * 128 + lo5;
    #pragma unroll
    for (int r = 0; r < 16; ++r) {
        const int row = (r & 3) + 8 * (r >> 2) + 4 * hi1;
        pp[row * 1024]      = acc0[r];
        pp[row * 1024 + 32] = acc1[r];
        pp[row * 1024 + 64] = acc2[r];
        pp[row * 1024 + 96] = acc3[r];
    }
}

// ---------------- K3b: reduce 13 partials + bias + LIF scan over t ----------------
__global__ __launch_bounds__(256) void k3b_lif(
    const float* __restrict__ part,  // [13][512][1024], col = t*32+b
    const float* __restrict__ fb,
    float* __restrict__ za)          // [32t][500][32]
{
    const int idx = blockIdx.x * 256 + threadIdx.x;
    if (idx >= 16000) return;
    const int n = idx >> 5, b = idx & 31;
    const float bias = fb[n];

    float v = 0.f, cu = 0.f;
    for (int t = 0; t < T_STEPS; ++t) {
        float s = 0.f;
        #pragma unroll
        for (int p = 0; p < 13; ++p)
            s += part[(size_t)p * 524288 + n * 1024 + t * 32 + b];
        s += bias;

        const float vd = v + 0.1f * (cu - v);
        const float id = 0.8f * cu;
        const float z = (vd - 1.0f > 0.0f) ? 1.0f : 0.0f;
        v = (z > 0.f) ? 0.f : vd;
        cu = id + s;
        za[(size_t)t * 16000 + idx] = z;
    }
}

// ---------------- K4: readout dots per (c,t) ----------------
__global__ __launch_bounds__(256) void k4_dot(
    const float* __restrict__ za,
    const float* __restrict__ ow,
    float* __restrict__ dota)
{
    const int c = blockIdx.x, t = blockIdx.y;
    const int tid = threadIdx.x;
    const int b = tid & 31, nc = tid >> 5;
    const float* __restrict__ wr = ow + c * 500;
    const float* __restrict__ zt = za + (size_t)t * 16000;

    float acc = 0.f;
    for (int j = 0; j < 63; ++j) {
        const int n = nc * 63 + j;
        if (n < 500) acc = fmaf(zt[n * 32 + b], wr[n], acc);
    }

    __shared__ float red[256];
    red[tid] = acc;
    __syncthreads();
    if (tid < 32) {
        float dot = 0.f;
        #pragma unroll
        for (int q = 0; q < 8; ++q) dot += red[q * 32 + tid];
        dota[((size_t)t * 10 + c) * 32 + tid] = dot;
    }
}

// ---------------- K5: LI scan + output ----------------
__global__ __launch_bounds__(320) void k5_li(
    const float* __restrict__ dota,
    float* __restrict__ outp)
{
    const int tid = threadIdx.x;
    if (tid >= 320) return;
    const int c = tid / 32, b = tid & 31;

    float vo = 0.f, io = 0.f;
    for (int t = 0; t < T_STEPS; ++t) {
        const float vout = vo + 0.1f * (io - vo);
        outp[t * 320 + b * 10 + c] = vout;
        vo = vout;
        io = 0.8f * io + dota[(t * 10 + c) * 32 + b];
    }
}

extern "C" void kernel_launch(void* const* d_in, const int* in_sizes, int n_in,
                              void* d_out, int out_size, void* d_ws, size_t ws_size,
                              hipStream_t stream) {
    const float* x  = (const float*)d_in[0];
    const float* w1 = (const float*)d_in[1];
    const float* b1 = (const float*)d_in[2];
    const float* w2 = (const float*)d_in[3];
    const float* b2 = (const float*)d_in[4];
    const float* fw = (const float*)d_in[5];
    const float* fb = (const float*)d_in[6];
    const float* ow = (const float*)d_in[7];
    float* out = (float*)d_out;
    float* ws = (float*)d_ws;

    size_t off = 0;
    float* zp1a = ws + off; off += 14745600;  // zp1c packed; zb overlay after k2a
    float* za   = ws + off; off += 512000;
    float* dota = ws + off; off += 10240;
    unsigned short* wsplit = (unsigned short*)(ws + off); off += 19200;
    float* wfbuf = ws + off; off += 4153344;  // wf: 8.3M u16 (written in prep, before k1)
    float* big  = ws + off; off += 22151168;  // union: xT(4.2M)/conv2raw(22.2M)/part(6.8M)
    // ~166 MB total; every region fully written before read.

    float* xT       = big;
    float* conv2raw = big;
    float* part     = big;
    unsigned short* zp1c16 = (unsigned short*)zp1a;  // [32t][2][900][4p][32b] packed
    unsigned short* zb = (unsigned short*)zp1a;      // overlay, zp1c dead after k2a
    unsigned short* wf = (unsigned short*)wfbuf;

    k_prep   <<<2774, 256, 0, stream>>>(x, xT, w2, wsplit, fw, wf);
    k1_conv1 <<<900, 256, 0, stream>>>(xT, w1, b1, zp1c16);
    k2a_mfma <<<5408, 64, 0, stream>>>((const unsigned*)zp1c16, wsplit, conv2raw);
    k2b_lifpool<<<676, 256, 0, stream>>>(conv2raw, b2, zb);   // zp1c dead after k2a
    k3_mfma  <<<416, 256, 0, stream>>>(wf, zb, part);
    k3b_lif  <<<63, 256, 0, stream>>>(part, fb, za);
    k4_dot   <<<dim3(10, 32), 256, 0, stream>>>(za, ow, dota);
    k5_li    <<<1, 320, 0, stream>>>(dota, out);
}

// Round 20
// 203.777 us; speedup vs baseline: 1.1607x; 1.0175x over previous
//
#include <hip/hip_runtime.h>

// SNN: v_dec = v + 0.1*(i - v); i_dec = 0.8*i; spike if v_dec > 1.0
// v' = spike ? 0 : v_dec; i' = i_dec + input.

#define T_STEPS 32

typedef __bf16 bf16x8 __attribute__((ext_vector_type(8)));
typedef float f32x16 __attribute__((ext_vector_type(16)));
typedef int i32x4 __attribute__((ext_vector_type(4)));

// Bijective XCD-chunked block swizzle (m204).
__device__ __forceinline__ int xcd_swz(int orig, int nwg) {
    const int q = nwg >> 3, r = nwg & 7;
    const int xcd = orig & 7, idx = orig >> 3;
    return (xcd < r ? xcd * (q + 1) : r * (q + 1) + (xcd - r) * q) + idx;
}

// ---------------- K_prep: fused {x-transpose, conv2-wsplit, fc-wsplit} ----------------
// bid <2048: transpose; <2098: k2w; else k3w (coalesced tile version).
__global__ __launch_bounds__(256) void k_prep(
    const float* __restrict__ x,  float* __restrict__ xT,
    const float* __restrict__ w2, unsigned short* __restrict__ wsplit,
    const float* __restrict__ fw, unsigned short* __restrict__ wf)
{
    __shared__ float shbuf[32 * 209];   // union: transpose tile[32][65] / fw tile[32][209]
    const int bid = blockIdx.x;
    const int tid = threadIdx.x;

    if (bid < 2048) {
        float (*tile)[65] = (float(*)[65])shbuf;
        const int y = bid & 63, t = bid >> 6;
        const int lx = tid & 63, bg = tid >> 6;
        #pragma unroll
        for (int p = 0; p < 8; ++p) {
            const int b = bg + p * 4;
            tile[b][lx] = x[((size_t)(t * 32 + b) * 64 + y) * 64 + lx];
        }
        __syncthreads();
        const int wb = tid & 31, xg = tid >> 5;
        #pragma unroll
        for (int p = 0; p < 8; ++p) {
            const int xx = xg + p * 8;
            xT[((size_t)(t * 64 + y) * 64 + xx) * 32 + wb] = tile[wb][xx];
        }
    } else if (bid < 2098) {
        const int i = (bid - 2048) * 256 + tid;
        if (i < 12800) {
            const int co = i / 400, rest = i % 400;
            const int ci = rest / 25, tap = rest % 25;
            const float w = w2[i];
            const unsigned wb = __float_as_uint(w);
            const unsigned hi = wb & 0xFFFF0000u;
            const float r1 = w - __uint_as_float(hi);
            const unsigned mid = __float_as_uint(r1) & 0xFFFF0000u;
            const float r2 = r1 - __uint_as_float(mid);
            const unsigned lo = __float_as_uint(r2) & 0xFFFF0000u;
            const int base = (tap * 32 + co) * 16 + ci;
            wsplit[base]         = (unsigned short)(hi >> 16);
            wsplit[12800 + base] = (unsigned short)(mid >> 16);
            wsplit[25600 + base] = (unsigned short)(lo >> 16);
        }
    } else {
        // ---- FC weight split, COALESCED: 416 blocks = 16 nt x 26 ks-chunks(13 ks) ----
        float (*tile)[209] = (float(*)[209])shbuf;   // [32n][208k+1 pad]
        const int j = bid - 2098;
        const int nt = j / 26, kb13 = j % 26;        // ks range [kb13*13, +13)

        // stage: 32 rows x 208 k, float4 reads coalesced along k
        for (int i = tid; i < 1664; i += 256) {
            const int r = i / 52, c4 = i - r * 52;
            const int n = nt * 32 + r;
            float4 val = make_float4(0.f, 0.f, 0.f, 0.f);
            if (n < 500)
                val = *(const float4*)(fw + (size_t)n * 5408 + kb13 * 208 + c4 * 4);
            tile[r][c4 * 4]     = val.x;
            tile[r][c4 * 4 + 1] = val.y;
            tile[r][c4 * 4 + 2] = val.z;
            tile[r][c4 * 4 + 3] = val.w;
        }
        __syncthreads();

        // pack: 13 ks x 32 n tasks; identical split math + output layout as before
        i32x4* __restrict__ wv = (i32x4*)wf;
        for (int j2 = tid; j2 < 416; j2 += 256) {
            const int ks_l = j2 >> 5, n_l = j2 & 31;
            const int ks = kb13 * 13 + ks_l;

            unsigned hipk[8], midpk[8], lopk[8];
            #pragma unroll
            for (int p = 0; p < 8; ++p) {
                unsigned h[2], m[2], o[2];
                #pragma unroll
                for (int e = 0; e < 2; ++e) {
                    const float w = tile[n_l][ks_l * 16 + 2 * p + e];
                    const unsigned wb = __float_as_uint(w);
                    const unsigned hi = wb & 0xFFFF0000u;
                    const float r1 = w - __uint_as_float(hi);
                    const unsigned mid = __float_as_uint(r1) & 0xFFFF0000u;
                    const float r2 = r1 - __uint_as_float(mid);
                    h[e] = hi >> 16; m[e] = mid >> 16; o[e] = __float_as_uint(r2) >> 16;
                }
                hipk[p]  = h[0] | (h[1] << 16);
                midpk[p] = m[0] | (m[1] << 16);
                lopk[p]  = o[0] | (o[1] << 16);
            }

            const int base = (nt * 338 + ks) * 64 + n_l * 2;  // i32x4 units
            i32x4 a, bq;
            a[0]=(int)hipk[0];a[1]=(int)hipk[1];a[2]=(int)hipk[2];a[3]=(int)hipk[3];
            bq[0]=(int)hipk[4];bq[1]=(int)hipk[5];bq[2]=(int)hipk[6];bq[3]=(int)hipk[7];
            wv[base] = a; wv[base + 1] = bq;
            a[0]=(int)midpk[0];a[1]=(int)midpk[1];a[2]=(int)midpk[2];a[3]=(int)midpk[3];
            bq[0]=(int)midpk[4];bq[1]=(int)midpk[5];bq[2]=(int)midpk[6];bq[3]=(int)midpk[7];
            wv[base + 346112] = a; wv[base + 346113] = bq;
            a[0]=(int)lopk[0];a[1]=(int)lopk[1];a[2]=(int)lopk[2];a[3]=(int)lopk[3];
            bq[0]=(int)lopk[4];bq[1]=(int)lopk[5];bq[2]=(int)lopk[6];bq[3]=(int)lopk[7];
            wv[base + 692224] = a; wv[base + 692225] = bq;
        }
    }
}

// ---------------- K1: conv1 (1->16) + LIF + pool, ALL timesteps (65us verified) ----
__global__ __launch_bounds__(256) void k1_conv1(
    const float* __restrict__ xT,    // [32t,64,64,32b]
    const float* __restrict__ w1,    // [16,1,5,5]
    const float* __restrict__ b1,    // [16]
    unsigned short* __restrict__ zp1c)
{
    const int pos = xcd_swz(blockIdx.x, 900);
    const int py = pos / 30, px = pos % 30;
    const int y0 = 2 * py, x0 = 2 * px;
    const int tid = threadIdx.x;
    const int b = tid & 31, slot = tid >> 5;

    __shared__ float win2[8 * 18 * 64];   // [8tt][18p][32b][2] = 36 KB

    float wreg[2][25];
    #pragma unroll
    for (int k = 0; k < 25; ++k) {
        wreg[0][k] = w1[slot * 25 + k];
        wreg[1][k] = w1[(slot + 8) * 25 + k];
    }
    const float bias0 = b1[slot], bias1 = b1[slot + 8];

    float v[2][4] = {{0.f,0.f,0.f,0.f},{0.f,0.f,0.f,0.f}};
    float cu[2][4] = {{0.f,0.f,0.f,0.f},{0.f,0.f,0.f,0.f}};

    const size_t obase = (size_t)pos * 256 + (slot >> 1) * 64 + b * 2 + (slot & 1);

    for (int tp = 0; tp < 4; ++tp) {
        __syncthreads();
        for (int i = tid; i < 1152; i += 256) {
            const int tt2 = i / 144;
            const int rem = i - tt2 * 144;
            const int p = rem >> 3, bq = rem & 7;
            const int r = p / 3, cpair = p - r * 3;
            const int b0 = bq * 4;
            const float* __restrict__ s0 = xT +
                ((size_t)((tp * 8 + tt2) * 64 + y0 + r) * 64 + (x0 + 2 * cpair)) * 32 + b0;
            const float4 v0 = *(const float4*)s0;
            const float4 v1 = *(const float4*)(s0 + 32);
            float2* __restrict__ d =
                (float2*)win2 + ((tt2 * 18 + p) * 32 + b0);
            d[0] = make_float2(v0.x, v1.x);
            d[1] = make_float2(v0.y, v1.y);
            d[2] = make_float2(v0.z, v1.z);
            d[3] = make_float2(v0.w, v1.w);
        }
        __syncthreads();

        for (int tt = 0; tt < 8; ++tt) {
            const int t = tp * 8 + tt;
            float xr[36];
            #pragma unroll
            for (int p = 0; p < 18; ++p) {
                const float2 u = ((const float2*)win2)[(tt * 18 + p) * 32 + b];
                const int r = p / 3, cpair = p - r * 3;
                xr[r * 6 + 2 * cpair]     = u.x;
                xr[r * 6 + 2 * cpair + 1] = u.y;
            }

            float acc0[4] = {0.f, 0.f, 0.f, 0.f};
            float acc1[4] = {0.f, 0.f, 0.f, 0.f};
            #pragma unroll
            for (int ky = 0; ky < 5; ++ky) {
                #pragma unroll
                for (int kx = 0; kx < 5; ++kx) {
                    const int tap = ky * 5 + kx;
                    const float e00 = xr[ky * 6 + kx];
                    const float e01 = xr[ky * 6 + kx + 1];
                    const float e10 = xr[(ky + 1) * 6 + kx];
                    const float e11 = xr[(ky + 1) * 6 + kx + 1];
                    const float w0 = wreg[0][tap];
                    acc0[0] = fmaf(w0, e00, acc0[0]);
                    acc0[1] = fmaf(w0, e01, acc0[1]);
                    acc0[2] = fmaf(w0, e10, acc0[2]);
                    acc0[3] = fmaf(w0, e11, acc0[3]);
                    const float w1v = wreg[1][tap];
                    acc1[0] = fmaf(w1v, e00, acc1[0]);
                    acc1[1] = fmaf(w1v, e01, acc1[1]);
                    acc1[2] = fmaf(w1v, e10, acc1[2]);
                    acc1[3] = fmaf(w1v, e11, acc1[3]);
                }
            }

            #pragma unroll
            for (int half = 0; half < 2; ++half) {
                const float* acc = half ? acc1 : acc0;
                const float bias = half ? bias1 : bias0;
                float zmax = 0.f;
                #pragma unroll
                for (int q = 0; q < 4; ++q) {
                    const float inp = acc[q] + bias;
                    const float vv = v[half][q], curr = cu[half][q];
                    const float vd = vv + 0.1f * (curr - vv);
                    const float id = 0.8f * curr;
                    const float z = (vd - 1.0f > 0.0f) ? 1.0f : 0.0f;
                    v[half][q] = (z > 0.f) ? 0.f : vd;
                    cu[half][q] = id + inp;
                    zmax = fmaxf(zmax, z);
                }
                zp1c[(size_t)t * 460800 + (size_t)half * 230400 + obase] =
                    (unsigned short)(__float_as_uint(zmax) >> 16);  // bf16 of 0/1 exact
            }
        }
    }
}

// ---------------- K2a: conv2 as MFMA GEMM (unfused), 1 wave/block, no LDS ----------------
__global__ __launch_bounds__(64) void k2a_mfma(
    const unsigned* __restrict__ zp1c,       // [32t][2cig][30][30][4p][32b] u32
    const unsigned short* __restrict__ wsplit,
    float* __restrict__ raw)                 // [32t][169pg][4q][32co][32b]
{
    const int l = threadIdx.x;
    const int task = xcd_swz(blockIdx.x, 5408);
    const int t = task / 169, pg = task % 169;
    const int py = pg / 13, px = pg % 13;
    const int b = l & 31, cig = l >> 5;
    const int abase = (l & 31) * 2 + cig;

    const i32x4* __restrict__ wv = (const i32x4*)wsplit;

    const unsigned* __restrict__ zt =
        zp1c + (size_t)(t * 2 + cig) * 115200 + ((2 * py) * 30 + 2 * px) * 128 + b;

    f32x16 accA, accB, accC, accD;
    #pragma unroll
    for (int r = 0; r < 16; ++r) { accA[r] = 0.f; accB[r] = 0.f; accC[r] = 0.f; accD[r] = 0.f; }

    #pragma unroll
    for (int wy = 0; wy < 6; ++wy) {
        i32x4 bw[6];
        #pragma unroll
        for (int wx = 0; wx < 6; ++wx) {
            const unsigned* __restrict__ c = zt + (wy * 30 + wx) * 128;
            bw[wx][0] = (int)c[0];
            bw[wx][1] = (int)c[32];
            bw[wx][2] = (int)c[64];
            bw[wx][3] = (int)c[96];
        }
        if (wy <= 4) {
            #pragma unroll
            for (int sp = 0; sp < 3; ++sp) {
                #pragma unroll
                for (int kx = 0; kx < 5; ++kx) {
                    const int tap = wy * 5 + kx;
                    const bf16x8 A = __builtin_bit_cast(bf16x8, wv[(sp * 25 + tap) * 64 + abase]);
                    accA = __builtin_amdgcn_mfma_f32_32x32x16_bf16(
                        A, __builtin_bit_cast(bf16x8, bw[kx]),     accA, 0, 0, 0);
                    accB = __builtin_amdgcn_mfma_f32_32x32x16_bf16(
                        A, __builtin_bit_cast(bf16x8, bw[kx + 1]), accB, 0, 0, 0);
                }
            }
        }
        if (wy >= 1) {
            #pragma unroll
            for (int sp = 0; sp < 3; ++sp) {
                #pragma unroll
                for (int kx = 0; kx < 5; ++kx) {
                    const int tap = (wy - 1) * 5 + kx;
                    const bf16x8 A = __builtin_bit_cast(bf16x8, wv[(sp * 25 + tap) * 64 + abase]);
                    accC = __builtin_amdgcn_mfma_f32_32x32x16_bf16(
                        A, __builtin_bit_cast(bf16x8, bw[kx]),     accC, 0, 0, 0);
                    accD = __builtin_amdgcn_mfma_f32_32x32x16_bf16(
                        A, __builtin_bit_cast(bf16x8, bw[kx + 1]), accD, 0, 0, 0);
                }
            }
        }
    }

    float* __restrict__ rp = raw + (size_t)(t * 169 + pg) * 4096 + b;
    const int hi = l >> 5;
    #pragma unroll
    for (int r = 0; r < 16; ++r) {
        const int row = (r & 3) + 8 * (r >> 2) + 4 * hi;
        rp[row * 32]        = accA[r];
        rp[1024 + row * 32] = accB[r];
        rp[2048 + row * 32] = accC[r];
        rp[3072 + row * 32] = accD[r];
    }
}

// ---------------- K2b: LIF + pool scan over t; writes packed bf16 zb directly ----------
__global__ __launch_bounds__(256) void k2b_lifpool(
    const float* __restrict__ raw,   // [32t][169pg][4q][32co][32b]
    const float* __restrict__ b2,
    unsigned short* __restrict__ zb) // [32t][338ks][2kh][32b][8k8]
{
    const int bid = blockIdx.x;
    const int pg = bid >> 2, cog = bid & 3;
    const int tid = threadIdx.x;
    const int co = cog * 8 + (tid >> 5), b = tid & 31;
    const float bias = b2[co];
    const float* __restrict__ rp = raw + (size_t)pg * 4096 + co * 32 + b;

    const int k = co * 169 + pg;
    const size_t zidx0 = ((size_t)((k >> 4) * 2 + ((k >> 3) & 1)) * 32 + b) * 8 + (k & 7);

    float v0=0.f,v1=0.f,v2=0.f,v3=0.f, c0=0.f,c1=0.f,c2=0.f,c3=0.f;
    for (int t = 0; t < T_STEPS; ++t) {
        const float* __restrict__ r = rp + (size_t)t * 692224;
        float zm = 0.f;
        { const float inp = 10.f*(r[0]    + bias); const float vd = v0 + 0.1f*(c0-v0);
          const float z = (vd-1.f>0.f)?1.f:0.f; v0 = (z>0.f)?0.f:vd; c0 = 0.8f*c0 + inp;
          zm = fmaxf(zm, z); }
        { const float inp = 10.f*(r[1024] + bias); const float vd = v1 + 0.1f*(c1-v1);
          const float z = (vd-1.f>0.f)?1.f:0.f; v1 = (z>0.f)?0.f:vd; c1 = 0.8f*c1 + inp;
          zm = fmaxf(zm, z); }
        { const float inp = 10.f*(r[2048] + bias); const float vd = v2 + 0.1f*(c2-v2);
          const float z = (vd-1.f>0.f)?1.f:0.f; v2 = (z>0.f)?0.f:vd; c2 = 0.8f*c2 + inp;
          zm = fmaxf(zm, z); }
        { const float inp = 10.f*(r[3072] + bias); const float vd = v3 + 0.1f*(c3-v3);
          const float z = (vd-1.f>0.f)?1.f:0.f; v3 = (z>0.f)?0.f:vd; c3 = 0.8f*c3 + inp;
          zm = fmaxf(zm, z); }
        zb[(size_t)t * 173056 + zidx0] =
            (unsigned short)(__float_as_uint(zm) >> 16);  // bf16 of 0/1 exact
    }
}

// ---------------- K3: FC as MFMA GEMM, no LDS ----------------
__global__ __launch_bounds__(256) void k3_mfma(
    const unsigned short* __restrict__ wf,   // [3][16nt][338ks][32n][16k]
    const unsigned short* __restrict__ zb,   // [32t][338ks][2kh][32b][8k]
    float* __restrict__ part)                // [13][512][1024]
{
    const int wgid = xcd_swz(blockIdx.x, 416);
    const int ntg = wgid / 52, rest = wgid % 52;
    const int kc = rest >> 2, cgg = rest & 3;
    const int tid = threadIdx.x;
    const int w = tid >> 6, l = tid & 63;
    const int nt = ntg * 2 + (w >> 1);
    const int cg = cgg * 2 + (w & 1);
    const int lo5 = l & 31, hi1 = l >> 5;

    const i32x4* __restrict__ wv = (const i32x4*)wf;
    const i32x4* __restrict__ zv = (const i32x4*)zb;

    f32x16 acc0, acc1, acc2, acc3;
    #pragma unroll
    for (int r = 0; r < 16; ++r) { acc0[r]=0.f; acc1[r]=0.f; acc2[r]=0.f; acc3[r]=0.f; }

    const int ks0 = kc * 26;
    #pragma unroll 2
    for (int kk = 0; kk < 26; ++kk) {
        const int ks = ks0 + kk;
        const int ab = (nt * 338 + ks) * 64 + lo5 * 2 + hi1;
        const bf16x8 A0 = __builtin_bit_cast(bf16x8, wv[ab]);
        const bf16x8 A1 = __builtin_bit_cast(bf16x8, wv[ab + 346112]);
        const bf16x8 A2 = __builtin_bit_cast(bf16x8, wv[ab + 692224]);
        const int b0 = (((cg * 4) * 338 + ks) * 2 + hi1) * 32 + lo5;
        const bf16x8 B0 = __builtin_bit_cast(bf16x8, zv[b0]);
        const bf16x8 B1 = __builtin_bit_cast(bf16x8, zv[b0 + 21632]);
        const bf16x8 B2 = __builtin_bit_cast(bf16x8, zv[b0 + 43264]);
        const bf16x8 B3 = __builtin_bit_cast(bf16x8, zv[b0 + 64896]);
        acc0 = __builtin_amdgcn_mfma_f32_32x32x16_bf16(A0, B0, acc0, 0, 0, 0);
        acc1 = __builtin_amdgcn_mfma_f32_32x32x16_bf16(A0, B1, acc1, 0, 0, 0);
        acc2 = __builtin_amdgcn_mfma_f32_32x32x16_bf16(A0, B2, acc2, 0, 0, 0);
        acc3 = __builtin_amdgcn_mfma_f32_32x32x16_bf16(A0, B3, acc3, 0, 0, 0);
        acc0 = __builtin_amdgcn_mfma_f32_32x32x16_bf16(A1, B0, acc0, 0, 0, 0);
        acc1 = __builtin_amdgcn_mfma_f32_32x32x16_bf16(A1, B1, acc1, 0, 0, 0);
        acc2 = __builtin_amdgcn_mfma_f32_32x32x16_bf16(A1, B2, acc2, 0, 0, 0);
        acc3 = __builtin_amdgcn_mfma_f32_32x32x16_bf16(A1, B3, acc3, 0, 0, 0);
        acc0 = __builtin_amdgcn_mfma_f32_32x32x16_bf16(A2, B0, acc0, 0, 0, 0);
        acc1 = __builtin_amdgcn_mfma_f32_32x32x16_bf16(A2, B1, acc1, 0, 0, 0);
        acc2 = __builtin_amdgcn_mfma_f32_32x32x16_bf16(A2, B2, acc2, 0, 0, 0);
        acc3 = __builtin_amdgcn_mfma_f32_32x32x16_bf16(A2, B3, acc3, 0, 0, 0);
    }

    float* __restrict__ pp = part + ((size_t)(kc * 512 + nt * 32)) * 1024 + cg * 128 + lo5;
    #pragma unroll
    for (int r = 0; r < 16; ++r) {
        const int row = (r & 3) + 8 * (r >> 2) + 4 * hi1;
        pp[row * 1024]      = acc0[r];
        pp[row * 1024 + 32] = acc1[r];
        pp[row * 1024 + 64] = acc2[r];
        pp[row * 1024 + 96] = acc3[r];
    }
}

// ---------------- K3b: reduce 13 partials + bias + LIF scan over t ----------------
__global__ __launch_bounds__(256) void k3b_lif(
    const float* __restrict__ part,  // [13][512][1024], col = t*32+b
    const float* __restrict__ fb,
    float* __restrict__ za)          // [32t][500][32]
{
    const int idx = blockIdx.x * 256 + threadIdx.x;
    if (idx >= 16000) return;
    const int n = idx >> 5, b = idx & 31;
    const float bias = fb[n];

    float v = 0.f, cu = 0.f;
    for (int t = 0; t < T_STEPS; ++t) {
        float s = 0.f;
        #pragma unroll
        for (int p = 0; p < 13; ++p)
            s += part[(size_t)p * 524288 + n * 1024 + t * 32 + b];
        s += bias;

        const float vd = v + 0.1f * (cu - v);
        const float id = 0.8f * cu;
        const float z = (vd - 1.0f > 0.0f) ? 1.0f : 0.0f;
        v = (z > 0.f) ? 0.f : vd;
        cu = id + s;
        za[(size_t)t * 16000 + idx] = z;
    }
}

// ---------------- K4: readout dots per (c,t) ----------------
__global__ __launch_bounds__(256) void k4_dot(
    const float* __restrict__ za,
    const float* __restrict__ ow,
    float* __restrict__ dota)
{
    const int c = blockIdx.x, t = blockIdx.y;
    const int tid = threadIdx.x;
    const int b = tid & 31, nc = tid >> 5;
    const float* __restrict__ wr = ow + c * 500;
    const float* __restrict__ zt = za + (size_t)t * 16000;

    float acc = 0.f;
    for (int j = 0; j < 63; ++j) {
        const int n = nc * 63 + j;
        if (n < 500) acc = fmaf(zt[n * 32 + b], wr[n], acc);
    }

    __shared__ float red[256];
    red[tid] = acc;
    __syncthreads();
    if (tid < 32) {
        float dot = 0.f;
        #pragma unroll
        for (int q = 0; q < 8; ++q) dot += red[q * 32 + tid];
        dota[((size_t)t * 10 + c) * 32 + tid] = dot;
    }
}

// ---------------- K5: LI scan + output ----------------
__global__ __launch_bounds__(320) void k5_li(
    const float* __restrict__ dota,
    float* __restrict__ outp)
{
    const int tid = threadIdx.x;
    if (tid >= 320) return;
    const int c = tid / 32, b = tid & 31;

    float vo = 0.f, io = 0.f;
    for (int t = 0; t < T_STEPS; ++t) {
        const float vout = vo + 0.1f * (io - vo);
        outp[t * 320 + b * 10 + c] = vout;
        vo = vout;
        io = 0.8f * io + dota[(t * 10 + c) * 32 + b];
    }
}

extern "C" void kernel_launch(void* const* d_in, const int* in_sizes, int n_in,
                              void* d_out, int out_size, void* d_ws, size_t ws_size,
                              hipStream_t stream) {
    const float* x  = (const float*)d_in[0];
    const float* w1 = (const float*)d_in[1];
    const float* b1 = (const float*)d_in[2];
    const float* w2 = (const float*)d_in[3];
    const float* b2 = (const float*)d_in[4];
    const float* fw = (const float*)d_in[5];
    const float* fb = (const float*)d_in[6];
    const float* ow = (const float*)d_in[7];
    float* out = (float*)d_out;
    float* ws = (float*)d_ws;

    size_t off = 0;
    float* zp1a = ws + off; off += 14745600;  // zp1c packed; zb overlay after k2a
    float* za   = ws + off; off += 512000;
    float* dota = ws + off; off += 10240;
    unsigned short* wsplit = (unsigned short*)(ws + off); off += 19200;
    float* wfbuf = ws + off; off += 4153344;  // wf: 8.3M u16 (written in prep, before k1)
    float* big  = ws + off; off += 22151168;  // union: xT(4.2M)/conv2raw(22.2M)/part(6.8M)
    // ~166 MB total; every region fully written before read.

    float* xT       = big;
    float* conv2raw = big;
    float* part     = big;
    unsigned short* zp1c16 = (unsigned short*)zp1a;  // [32t][2][900][4p][32b] packed
    unsigned short* zb = (unsigned short*)zp1a;      // overlay, zp1c dead after k2a
    unsigned short* wf = (unsigned short*)wfbuf;

    k_prep   <<<2514, 256, 0, stream>>>(x, xT, w2, wsplit, fw, wf);
    k1_conv1 <<<900, 256, 0, stream>>>(xT, w1, b1, zp1c16);
    k2a_mfma <<<5408, 64, 0, stream>>>((const unsigned*)zp1c16, wsplit, conv2raw);
    k2b_lifpool<<<676, 256, 0, stream>>>(conv2raw, b2, zb);   // zp1c dead after k2a
    k3_mfma  <<<416, 256, 0, stream>>>(wf, zb, part);
    k3b_lif  <<<63, 256, 0, stream>>>(part, fb, za);
    k4_dot   <<<dim3(10, 32), 256, 0, stream>>>(za, ow, dota);
    k5_li    <<<1, 320, 0, stream>>>(dota, out);
}

// Round 21
// 201.141 us; speedup vs baseline: 1.1759x; 1.0131x over previous
//
#include <hip/hip_runtime.h>

// SNN: v_dec = v + 0.1*(i - v); i_dec = 0.8*i; spike if v_dec > 1.0
// v' = spike ? 0 : v_dec; i' = i_dec + input.

#define T_STEPS 32

typedef __bf16 bf16x8 __attribute__((ext_vector_type(8)));
typedef float f32x16 __attribute__((ext_vector_type(16)));
typedef int i32x4 __attribute__((ext_vector_type(4)));

// Bijective XCD-chunked block swizzle (m204).
__device__ __forceinline__ int xcd_swz(int orig, int nwg) {
    const int q = nwg >> 3, r = nwg & 7;
    const int xcd = orig & 7, idx = orig >> 3;
    return (xcd < r ? xcd * (q + 1) : r * (q + 1) + (xcd - r) * q) + idx;
}

// ---------------- K_prep: fused {x-transpose, conv2-wsplit, fc-wsplit} ----------------
__global__ __launch_bounds__(256) void k_prep(
    const float* __restrict__ x,  float* __restrict__ xT,
    const float* __restrict__ w2, unsigned short* __restrict__ wsplit,
    const float* __restrict__ fw, unsigned short* __restrict__ wf)
{
    __shared__ float shbuf[32 * 209];
    const int bid = blockIdx.x;
    const int tid = threadIdx.x;

    if (bid < 2048) {
        float (*tile)[65] = (float(*)[65])shbuf;
        const int y = bid & 63, t = bid >> 6;
        const int lx = tid & 63, bg = tid >> 6;
        #pragma unroll
        for (int p = 0; p < 8; ++p) {
            const int b = bg + p * 4;
            tile[b][lx] = x[((size_t)(t * 32 + b) * 64 + y) * 64 + lx];
        }
        __syncthreads();
        const int wb = tid & 31, xg = tid >> 5;
        #pragma unroll
        for (int p = 0; p < 8; ++p) {
            const int xx = xg + p * 8;
            xT[((size_t)(t * 64 + y) * 64 + xx) * 32 + wb] = tile[wb][xx];
        }
    } else if (bid < 2098) {
        const int i = (bid - 2048) * 256 + tid;
        if (i < 12800) {
            const int co = i / 400, rest = i % 400;
            const int ci = rest / 25, tap = rest % 25;
            const float w = w2[i];
            const unsigned wb = __float_as_uint(w);
            const unsigned hi = wb & 0xFFFF0000u;
            const float r1 = w - __uint_as_float(hi);
            const unsigned mid = __float_as_uint(r1) & 0xFFFF0000u;
            const float r2 = r1 - __uint_as_float(mid);
            const unsigned lo = __float_as_uint(r2) & 0xFFFF0000u;
            const int base = (tap * 32 + co) * 16 + ci;
            wsplit[base]         = (unsigned short)(hi >> 16);
            wsplit[12800 + base] = (unsigned short)(mid >> 16);
            wsplit[25600 + base] = (unsigned short)(lo >> 16);
        }
    } else {
        float (*tile)[209] = (float(*)[209])shbuf;
        const int j = bid - 2098;
        const int nt = j / 26, kb13 = j % 26;

        for (int i = tid; i < 1664; i += 256) {
            const int r = i / 52, c4 = i - r * 52;
            const int n = nt * 32 + r;
            float4 val = make_float4(0.f, 0.f, 0.f, 0.f);
            if (n < 500)
                val = *(const float4*)(fw + (size_t)n * 5408 + kb13 * 208 + c4 * 4);
            tile[r][c4 * 4]     = val.x;
            tile[r][c4 * 4 + 1] = val.y;
            tile[r][c4 * 4 + 2] = val.z;
            tile[r][c4 * 4 + 3] = val.w;
        }
        __syncthreads();

        i32x4* __restrict__ wv = (i32x4*)wf;
        for (int j2 = tid; j2 < 416; j2 += 256) {
            const int ks_l = j2 >> 5, n_l = j2 & 31;
            const int ks = kb13 * 13 + ks_l;

            unsigned hipk[8], midpk[8], lopk[8];
            #pragma unroll
            for (int p = 0; p < 8; ++p) {
                unsigned h[2], m[2], o[2];
                #pragma unroll
                for (int e = 0; e < 2; ++e) {
                    const float w = tile[n_l][ks_l * 16 + 2 * p + e];
                    const unsigned wb = __float_as_uint(w);
                    const unsigned hi = wb & 0xFFFF0000u;
                    const float r1 = w - __uint_as_float(hi);
                    const unsigned mid = __float_as_uint(r1) & 0xFFFF0000u;
                    const float r2 = r1 - __uint_as_float(mid);
                    h[e] = hi >> 16; m[e] = mid >> 16; o[e] = __float_as_uint(r2) >> 16;
                }
                hipk[p]  = h[0] | (h[1] << 16);
                midpk[p] = m[0] | (m[1] << 16);
                lopk[p]  = o[0] | (o[1] << 16);
            }

            const int base = (nt * 338 + ks) * 64 + n_l * 2;
            i32x4 a, bq;
            a[0]=(int)hipk[0];a[1]=(int)hipk[1];a[2]=(int)hipk[2];a[3]=(int)hipk[3];
            bq[0]=(int)hipk[4];bq[1]=(int)hipk[5];bq[2]=(int)hipk[6];bq[3]=(int)hipk[7];
            wv[base] = a; wv[base + 1] = bq;
            a[0]=(int)midpk[0];a[1]=(int)midpk[1];a[2]=(int)midpk[2];a[3]=(int)midpk[3];
            bq[0]=(int)midpk[4];bq[1]=(int)midpk[5];bq[2]=(int)midpk[6];bq[3]=(int)midpk[7];
            wv[base + 346112] = a; wv[base + 346113] = bq;
            a[0]=(int)lopk[0];a[1]=(int)lopk[1];a[2]=(int)lopk[2];a[3]=(int)lopk[3];
            bq[0]=(int)lopk[4];bq[1]=(int)lopk[5];bq[2]=(int)lopk[6];bq[3]=(int)lopk[7];
            wv[base + 692224] = a; wv[base + 692225] = bq;
        }
    }
}

// ---------------- K1: conv1 (1->16) + LIF + pool, ALL timesteps (65us verified) ----
__global__ __launch_bounds__(256) void k1_conv1(
    const float* __restrict__ xT,    // [32t,64,64,32b]
    const float* __restrict__ w1,    // [16,1,5,5]
    const float* __restrict__ b1,    // [16]
    unsigned short* __restrict__ zp1c)
{
    const int pos = xcd_swz(blockIdx.x, 900);
    const int py = pos / 30, px = pos % 30;
    const int y0 = 2 * py, x0 = 2 * px;
    const int tid = threadIdx.x;
    const int b = tid & 31, slot = tid >> 5;

    __shared__ float win2[8 * 18 * 64];   // [8tt][18p][32b][2] = 36 KB

    float wreg[2][25];
    #pragma unroll
    for (int k = 0; k < 25; ++k) {
        wreg[0][k] = w1[slot * 25 + k];
        wreg[1][k] = w1[(slot + 8) * 25 + k];
    }
    const float bias0 = b1[slot], bias1 = b1[slot + 8];

    float v[2][4] = {{0.f,0.f,0.f,0.f},{0.f,0.f,0.f,0.f}};
    float cu[2][4] = {{0.f,0.f,0.f,0.f},{0.f,0.f,0.f,0.f}};

    const size_t obase = (size_t)pos * 256 + (slot >> 1) * 64 + b * 2 + (slot & 1);

    for (int tp = 0; tp < 4; ++tp) {
        __syncthreads();
        for (int i = tid; i < 1152; i += 256) {
            const int tt2 = i / 144;
            const int rem = i - tt2 * 144;
            const int p = rem >> 3, bq = rem & 7;
            const int r = p / 3, cpair = p - r * 3;
            const int b0 = bq * 4;
            const float* __restrict__ s0 = xT +
                ((size_t)((tp * 8 + tt2) * 64 + y0 + r) * 64 + (x0 + 2 * cpair)) * 32 + b0;
            const float4 v0 = *(const float4*)s0;
            const float4 v1 = *(const float4*)(s0 + 32);
            float2* __restrict__ d =
                (float2*)win2 + ((tt2 * 18 + p) * 32 + b0);
            d[0] = make_float2(v0.x, v1.x);
            d[1] = make_float2(v0.y, v1.y);
            d[2] = make_float2(v0.z, v1.z);
            d[3] = make_float2(v0.w, v1.w);
        }
        __syncthreads();

        for (int tt = 0; tt < 8; ++tt) {
            const int t = tp * 8 + tt;
            float xr[36];
            #pragma unroll
            for (int p = 0; p < 18; ++p) {
                const float2 u = ((const float2*)win2)[(tt * 18 + p) * 32 + b];
                const int r = p / 3, cpair = p - r * 3;
                xr[r * 6 + 2 * cpair]     = u.x;
                xr[r * 6 + 2 * cpair + 1] = u.y;
            }

            float acc0[4] = {0.f, 0.f, 0.f, 0.f};
            float acc1[4] = {0.f, 0.f, 0.f, 0.f};
            #pragma unroll
            for (int ky = 0; ky < 5; ++ky) {
                #pragma unroll
                for (int kx = 0; kx < 5; ++kx) {
                    const int tap = ky * 5 + kx;
                    const float e00 = xr[ky * 6 + kx];
                    const float e01 = xr[ky * 6 + kx + 1];
                    const float e10 = xr[(ky + 1) * 6 + kx];
                    const float e11 = xr[(ky + 1) * 6 + kx + 1];
                    const float w0 = wreg[0][tap];
                    acc0[0] = fmaf(w0, e00, acc0[0]);
                    acc0[1] = fmaf(w0, e01, acc0[1]);
                    acc0[2] = fmaf(w0, e10, acc0[2]);
                    acc0[3] = fmaf(w0, e11, acc0[3]);
                    const float w1v = wreg[1][tap];
                    acc1[0] = fmaf(w1v, e00, acc1[0]);
                    acc1[1] = fmaf(w1v, e01, acc1[1]);
                    acc1[2] = fmaf(w1v, e10, acc1[2]);
                    acc1[3] = fmaf(w1v, e11, acc1[3]);
                }
            }

            #pragma unroll
            for (int half = 0; half < 2; ++half) {
                const float* acc = half ? acc1 : acc0;
                const float bias = half ? bias1 : bias0;
                float zmax = 0.f;
                #pragma unroll
                for (int q = 0; q < 4; ++q) {
                    const float inp = acc[q] + bias;
                    const float vv = v[half][q], curr = cu[half][q];
                    const float vd = vv + 0.1f * (curr - vv);
                    const float id = 0.8f * curr;
                    const float z = (vd - 1.0f > 0.0f) ? 1.0f : 0.0f;
                    v[half][q] = (z > 0.f) ? 0.f : vd;
                    cu[half][q] = id + inp;
                    zmax = fmaxf(zmax, z);
                }
                zp1c[(size_t)t * 460800 + (size_t)half * 230400 + obase] =
                    (unsigned short)(__float_as_uint(zmax) >> 16);  // bf16 of 0/1 exact
            }
        }
    }
}

// ---------------- K2a: conv2 as MFMA GEMM (unfused), 1 wave/block, no LDS ----------------
// Output layout quadrant-MINOR: raw[t][pg][32row][32b][4q] -> float4 stores.
__global__ __launch_bounds__(64) void k2a_mfma(
    const unsigned* __restrict__ zp1c,       // [32t][2cig][30][30][4p][32b] u32
    const unsigned short* __restrict__ wsplit,
    float* __restrict__ raw)                 // [32t][169pg][32row][32b][4q]
{
    const int l = threadIdx.x;
    const int task = xcd_swz(blockIdx.x, 5408);
    const int t = task / 169, pg = task % 169;
    const int py = pg / 13, px = pg % 13;
    const int b = l & 31, cig = l >> 5;
    const int abase = (l & 31) * 2 + cig;

    const i32x4* __restrict__ wv = (const i32x4*)wsplit;

    const unsigned* __restrict__ zt =
        zp1c + (size_t)(t * 2 + cig) * 115200 + ((2 * py) * 30 + 2 * px) * 128 + b;

    f32x16 accA, accB, accC, accD;
    #pragma unroll
    for (int r = 0; r < 16; ++r) { accA[r] = 0.f; accB[r] = 0.f; accC[r] = 0.f; accD[r] = 0.f; }

    #pragma unroll
    for (int wy = 0; wy < 6; ++wy) {
        i32x4 bw[6];
        #pragma unroll
        for (int wx = 0; wx < 6; ++wx) {
            const unsigned* __restrict__ c = zt + (wy * 30 + wx) * 128;
            bw[wx][0] = (int)c[0];
            bw[wx][1] = (int)c[32];
            bw[wx][2] = (int)c[64];
            bw[wx][3] = (int)c[96];
        }
        if (wy <= 4) {
            #pragma unroll
            for (int sp = 0; sp < 3; ++sp) {
                #pragma unroll
                for (int kx = 0; kx < 5; ++kx) {
                    const int tap = wy * 5 + kx;
                    const bf16x8 A = __builtin_bit_cast(bf16x8, wv[(sp * 25 + tap) * 64 + abase]);
                    accA = __builtin_amdgcn_mfma_f32_32x32x16_bf16(
                        A, __builtin_bit_cast(bf16x8, bw[kx]),     accA, 0, 0, 0);
                    accB = __builtin_amdgcn_mfma_f32_32x32x16_bf16(
                        A, __builtin_bit_cast(bf16x8, bw[kx + 1]), accB, 0, 0, 0);
                }
            }
        }
        if (wy >= 1) {
            #pragma unroll
            for (int sp = 0; sp < 3; ++sp) {
                #pragma unroll
                for (int kx = 0; kx < 5; ++kx) {
                    const int tap = (wy - 1) * 5 + kx;
                    const bf16x8 A = __builtin_bit_cast(bf16x8, wv[(sp * 25 + tap) * 64 + abase]);
                    accC = __builtin_amdgcn_mfma_f32_32x32x16_bf16(
                        A, __builtin_bit_cast(bf16x8, bw[kx]),     accC, 0, 0, 0);
                    accD = __builtin_amdgcn_mfma_f32_32x32x16_bf16(
                        A, __builtin_bit_cast(bf16x8, bw[kx + 1]), accD, 0, 0, 0);
                }
            }
        }
    }

    // store: quadrants interleaved -> one float4 per C row
    float* __restrict__ rp = raw + (size_t)(t * 169 + pg) * 4096 + b * 4;
    const int hi = l >> 5;
    #pragma unroll
    for (int r = 0; r < 16; ++r) {
        const int row = (r & 3) + 8 * (r >> 2) + 4 * hi;
        float4 o;
        o.x = accA[r]; o.y = accB[r]; o.z = accC[r]; o.w = accD[r];
        *(float4*)&rp[row * 128] = o;
    }
}

// ---------------- K2b: LIF + pool scan over t; quadrant-minor float4 loads ----------
__global__ __launch_bounds__(256) void k2b_lifpool(
    const float* __restrict__ raw,   // [32t][169pg][32co][32b][4q]
    const float* __restrict__ b2,
    unsigned short* __restrict__ zb) // [32t][338ks][2kh][32b][8k8]
{
    const int bid = blockIdx.x;
    const int pg = bid >> 2, cog = bid & 3;
    const int tid = threadIdx.x;
    const int co = cog * 8 + (tid >> 5), b = tid & 31;
    const float bias = b2[co];
    const float* __restrict__ rp = raw + (size_t)pg * 4096 + co * 128 + b * 4;

    const int k = co * 169 + pg;
    const size_t zidx0 = ((size_t)((k >> 4) * 2 + ((k >> 3) & 1)) * 32 + b) * 8 + (k & 7);

    float v0=0.f,v1=0.f,v2=0.f,v3=0.f, c0=0.f,c1=0.f,c2=0.f,c3=0.f;
    for (int t = 0; t < T_STEPS; ++t) {
        const float4 r4 = *(const float4*)(rp + (size_t)t * 692224);
        float zm = 0.f;
        { const float inp = 10.f*(r4.x + bias); const float vd = v0 + 0.1f*(c0-v0);
          const float z = (vd-1.f>0.f)?1.f:0.f; v0 = (z>0.f)?0.f:vd; c0 = 0.8f*c0 + inp;
          zm = fmaxf(zm, z); }
        { const float inp = 10.f*(r4.y + bias); const float vd = v1 + 0.1f*(c1-v1);
          const float z = (vd-1.f>0.f)?1.f:0.f; v1 = (z>0.f)?0.f:vd; c1 = 0.8f*c1 + inp;
          zm = fmaxf(zm, z); }
        { const float inp = 10.f*(r4.z + bias); const float vd = v2 + 0.1f*(c2-v2);
          const float z = (vd-1.f>0.f)?1.f:0.f; v2 = (z>0.f)?0.f:vd; c2 = 0.8f*c2 + inp;
          zm = fmaxf(zm, z); }
        { const float inp = 10.f*(r4.w + bias); const float vd = v3 + 0.1f*(c3-v3);
          const float z = (vd-1.f>0.f)?1.f:0.f; v3 = (z>0.f)?0.f:vd; c3 = 0.8f*c3 + inp;
          zm = fmaxf(zm, z); }
        zb[(size_t)t * 173056 + zidx0] =
            (unsigned short)(__float_as_uint(zm) >> 16);  // bf16 of 0/1 exact
    }
}

// ---------------- K3: FC as MFMA GEMM, no LDS ----------------
__global__ __launch_bounds__(256) void k3_mfma(
    const unsigned short* __restrict__ wf,   // [3][16nt][338ks][32n][16k]
    const unsigned short* __restrict__ zb,   // [32t][338ks][2kh][32b][8k]
    float* __restrict__ part)                // [13][512][1024]
{
    const int wgid = xcd_swz(blockIdx.x, 416);
    const int ntg = wgid / 52, rest = wgid % 52;
    const int kc = rest >> 2, cgg = rest & 3;
    const int tid = threadIdx.x;
    const int w = tid >> 6, l = tid & 63;
    const int nt = ntg * 2 + (w >> 1);
    const int cg = cgg * 2 + (w & 1);
    const int lo5 = l & 31, hi1 = l >> 5;

    const i32x4* __restrict__ wv = (const i32x4*)wf;
    const i32x4* __restrict__ zv = (const i32x4*)zb;

    f32x16 acc0, acc1, acc2, acc3;
    #pragma unroll
    for (int r = 0; r < 16; ++r) { acc0[r]=0.f; acc1[r]=0.f; acc2[r]=0.f; acc3[r]=0.f; }

    const int ks0 = kc * 26;
    #pragma unroll 2
    for (int kk = 0; kk < 26; ++kk) {
        const int ks = ks0 + kk;
        const int ab = (nt * 338 + ks) * 64 + lo5 * 2 + hi1;
        const bf16x8 A0 = __builtin_bit_cast(bf16x8, wv[ab]);
        const bf16x8 A1 = __builtin_bit_cast(bf16x8, wv[ab + 346112]);
        const bf16x8 A2 = __builtin_bit_cast(bf16x8, wv[ab + 692224]);
        const int b0 = (((cg * 4) * 338 + ks) * 2 + hi1) * 32 + lo5;
        const bf16x8 B0 = __builtin_bit_cast(bf16x8, zv[b0]);
        const bf16x8 B1 = __builtin_bit_cast(bf16x8, zv[b0 + 21632]);
        const bf16x8 B2 = __builtin_bit_cast(bf16x8, zv[b0 + 43264]);
        const bf16x8 B3 = __builtin_bit_cast(bf16x8, zv[b0 + 64896]);
        acc0 = __builtin_amdgcn_mfma_f32_32x32x16_bf16(A0, B0, acc0, 0, 0, 0);
        acc1 = __builtin_amdgcn_mfma_f32_32x32x16_bf16(A0, B1, acc1, 0, 0, 0);
        acc2 = __builtin_amdgcn_mfma_f32_32x32x16_bf16(A0, B2, acc2, 0, 0, 0);
        acc3 = __builtin_amdgcn_mfma_f32_32x32x16_bf16(A0, B3, acc3, 0, 0, 0);
        acc0 = __builtin_amdgcn_mfma_f32_32x32x16_bf16(A1, B0, acc0, 0, 0, 0);
        acc1 = __builtin_amdgcn_mfma_f32_32x32x16_bf16(A1, B1, acc1, 0, 0, 0);
        acc2 = __builtin_amdgcn_mfma_f32_32x32x16_bf16(A1, B2, acc2, 0, 0, 0);
        acc3 = __builtin_amdgcn_mfma_f32_32x32x16_bf16(A1, B3, acc3, 0, 0, 0);
        acc0 = __builtin_amdgcn_mfma_f32_32x32x16_bf16(A2, B0, acc0, 0, 0, 0);
        acc1 = __builtin_amdgcn_mfma_f32_32x32x16_bf16(A2, B1, acc1, 0, 0, 0);
        acc2 = __builtin_amdgcn_mfma_f32_32x32x16_bf16(A2, B2, acc2, 0, 0, 0);
        acc3 = __builtin_amdgcn_mfma_f32_32x32x16_bf16(A2, B3, acc3, 0, 0, 0);
    }

    float* __restrict__ pp = part + ((size_t)(kc * 512 + nt * 32)) * 1024 + cg * 128 + lo5;
    #pragma unroll
    for (int r = 0; r < 16; ++r) {
        const int row = (r & 3) + 8 * (r >> 2) + 4 * hi1;
        pp[row * 1024]      = acc0[r];
        pp[row * 1024 + 32] = acc1[r];
        pp[row * 1024 + 64] = acc2[r];
        pp[row * 1024 + 96] = acc3[r];
    }
}

// ---------------- K3b: reduce 13 partials + bias + LIF scan over t ----------------
__global__ __launch_bounds__(256) void k3b_lif(
    const float* __restrict__ part,  // [13][512][1024], col = t*32+b
    const float* __restrict__ fb,
    float* __restrict__ za)          // [32t][500][32]
{
    const int idx = blockIdx.x * 256 + threadIdx.x;
    if (idx >= 16000) return;
    const int n = idx >> 5, b = idx & 31;
    const float bias = fb[n];

    float v = 0.f, cu = 0.f;
    for (int t = 0; t < T_STEPS; ++t) {
        float s = 0.f;
        #pragma unroll
        for (int p = 0; p < 13; ++p)
            s += part[(size_t)p * 524288 + n * 1024 + t * 32 + b];
        s += bias;

        const float vd = v + 0.1f * (cu - v);
        const float id = 0.8f * cu;
        const float z = (vd - 1.0f > 0.0f) ? 1.0f : 0.0f;
        v = (z > 0.f) ? 0.f : vd;
        cu = id + s;
        za[(size_t)t * 16000 + idx] = z;
    }
}

// ---------------- K4: readout dots per (c,t) ----------------
__global__ __launch_bounds__(256) void k4_dot(
    const float* __restrict__ za,
    const float* __restrict__ ow,
    float* __restrict__ dota)
{
    const int c = blockIdx.x, t = blockIdx.y;
    const int tid = threadIdx.x;
    const int b = tid & 31, nc = tid >> 5;
    const float* __restrict__ wr = ow + c * 500;
    const float* __restrict__ zt = za + (size_t)t * 16000;

    float acc = 0.f;
    for (int j = 0; j < 63; ++j) {
        const int n = nc * 63 + j;
        if (n < 500) acc = fmaf(zt[n * 32 + b], wr[n], acc);
    }

    __shared__ float red[256];
    red[tid] = acc;
    __syncthreads();
    if (tid < 32) {
        float dot = 0.f;
        #pragma unroll
        for (int q = 0; q < 8; ++q) dot += red[q * 32 + tid];
        dota[((size_t)t * 10 + c) * 32 + tid] = dot;
    }
}

// ---------------- K5: LI scan + output ----------------
__global__ __launch_bounds__(320) void k5_li(
    const float* __restrict__ dota,
    float* __restrict__ outp)
{
    const int tid = threadIdx.x;
    if (tid >= 320) return;
    const int c = tid / 32, b = tid & 31;

    float vo = 0.f, io = 0.f;
    for (int t = 0; t < T_STEPS; ++t) {
        const float vout = vo + 0.1f * (io - vo);
        outp[t * 320 + b * 10 + c] = vout;
        vo = vout;
        io = 0.8f * io + dota[(t * 10 + c) * 32 + b];
    }
}

extern "C" void kernel_launch(void* const* d_in, const int* in_sizes, int n_in,
                              void* d_out, int out_size, void* d_ws, size_t ws_size,
                              hipStream_t stream) {
    const float* x  = (const float*)d_in[0];
    const float* w1 = (const float*)d_in[1];
    const float* b1 = (const float*)d_in[2];
    const float* w2 = (const float*)d_in[3];
    const float* b2 = (const float*)d_in[4];
    const float* fw = (const float*)d_in[5];
    const float* fb = (const float*)d_in[6];
    const float* ow = (const float*)d_in[7];
    float* out = (float*)d_out;
    float* ws = (float*)d_ws;

    size_t off = 0;
    float* zp1a = ws + off; off += 14745600;  // zp1c packed; zb overlay after k2a
    float* za   = ws + off; off += 512000;
    float* dota = ws + off; off += 10240;
    unsigned short* wsplit = (unsigned short*)(ws + off); off += 19200;
    float* wfbuf = ws + off; off += 4153344;  // wf: 8.3M u16 (written in prep, before k1)
    float* big  = ws + off; off += 22151168;  // union: xT(4.2M)/conv2raw(22.2M)/part(6.8M)
    // ~166 MB total; every region fully written before read.

    float* xT       = big;
    float* conv2raw = big;
    float* part     = big;
    unsigned short* zp1c16 = (unsigned short*)zp1a;  // [32t][2][900][4p][32b] packed
    unsigned short* zb = (unsigned short*)zp1a;      // overlay, zp1c dead after k2a
    unsigned short* wf = (unsigned short*)wfbuf;

    k_prep   <<<2514, 256, 0, stream>>>(x, xT, w2, wsplit, fw, wf);
    k1_conv1 <<<900, 256, 0, stream>>>(xT, w1, b1, zp1c16);
    k2a_mfma <<<5408, 64, 0, stream>>>((const unsigned*)zp1c16, wsplit, conv2raw);
    k2b_lifpool<<<676, 256, 0, stream>>>(conv2raw, b2, zb);   // zp1c dead after k2a
    k3_mfma  <<<416, 256, 0, stream>>>(wf, zb, part);
    k3b_lif  <<<63, 256, 0, stream>>>(part, fb, za);
    k4_dot   <<<dim3(10, 32), 256, 0, stream>>>(za, ow, dota);
    k5_li    <<<1, 320, 0, stream>>>(dota, out);
}